// Round 9
// baseline (1294.117 us; speedup 1.0000x reference)
//
#include <hip/hip_runtime.h>
#include <hip/hip_bf16.h>
#include <cstdint>
#include <cstddef>

namespace {

constexpr int Hh = 512;
constexpr int G3 = 1536;   // 3*H
constexpr int Bb = 32;
constexpr int Tt = 64;
constexpr int Vv = 32000;

typedef __attribute__((ext_vector_type(8))) short short8;
typedef __attribute__((ext_vector_type(4))) float f32x4;
typedef unsigned long long ull;

__device__ __forceinline__ unsigned bf16bits(float f) {
  union { __hip_bfloat16 h; unsigned short u; } c;
  c.h = __float2bfloat16(f);
  return (unsigned)c.u;
}

// async global->LDS, 16B per lane; LDS dest = wave-uniform base + lane*16
__device__ __forceinline__ void gl_lds16(const void* g, void* l) {
  __builtin_amdgcn_global_load_lds(
      (const __attribute__((address_space(1))) unsigned int*)g,
      (__attribute__((address_space(3))) unsigned int*)l, 16, 0, 0);
}

// ---------------- f32 -> bf16 convert (vectorized) ----------------
__global__ void cvt_bf16_k(const float* __restrict__ src, __hip_bfloat16* __restrict__ dst, int n4) {
  int i = blockIdx.x * blockDim.x + threadIdx.x;
  if (i >= n4) return;
  float4 v = ((const float4*)src)[i];
  union { __hip_bfloat16 h[4]; uint2 u; } o;
  o.h[0] = __float2bfloat16(v.x);
  o.h[1] = __float2bfloat16(v.y);
  o.h[2] = __float2bfloat16(v.z);
  o.h[3] = __float2bfloat16(v.w);
  ((uint2*)dst)[i] = o.u;
}

// ---------------- pack Whh[1536][512] -> P[k][i] = {bf16 r, bf16 z | bf16 n, 0} uint2, 2MB ----------------
__global__ void pack_whh_bf_k(const float* __restrict__ Whh, uint2* __restrict__ P) {
  __shared__ float tw[3][32][65];
  const int k0 = blockIdx.x * 64, i0 = blockIdx.y * 32;
  const int t = threadIdx.x;               // 256
  const int kk = t & 63, r4 = t >> 6;
  for (int ri = r4; ri < 96; ri += 4) {
    const int g = ri >> 5, ii = ri & 31;
    tw[g][ii][kk] = Whh[(size_t)(g * 512 + i0 + ii) * 512 + k0 + kk];
  }
  __syncthreads();
  const int ii = t & 31, kq = t >> 5;
  for (int k2 = kq; k2 < 64; k2 += 8) {
    unsigned rb = bf16bits(tw[0][ii][k2]);
    unsigned zb = bf16bits(tw[1][ii][k2]);
    unsigned nb = bf16bits(tw[2][ii][k2]);
    P[(size_t)(k0 + k2) * 512 + i0 + ii] = make_uint2((zb << 16) | rb, nb);
  }
}

// ---------------- embedding gather (optionally relu) -> bf16 [2048][512] ----------------
__global__ void embed_k(const int* __restrict__ idx, const float* __restrict__ emb,
                        __hip_bfloat16* __restrict__ outp, int do_relu) {
  int row = blockIdx.x;            // 0..2047 (= b*64+t)
  int r = idx[row];
  float4 v = ((const float4*)(emb + (size_t)r * Hh))[threadIdx.x];  // 128 thr * 4
  if (do_relu) {
    v.x = fmaxf(v.x, 0.f); v.y = fmaxf(v.y, 0.f);
    v.z = fmaxf(v.z, 0.f); v.w = fmaxf(v.w, 0.f);
  }
  union { __hip_bfloat16 h[4]; uint2 u; } o;
  o.h[0] = __float2bfloat16(v.x);
  o.h[1] = __float2bfloat16(v.y);
  o.h[2] = __float2bfloat16(v.z);
  o.h[3] = __float2bfloat16(v.w);
  ((uint2*)(outp + (size_t)row * Hh))[threadIdx.x] = o.u;
}

// ---------------- zero u32 ----------------
__global__ void zero_k(unsigned* __restrict__ p, int n) {
  int i = blockIdx.x * blockDim.x + threadIdx.x;
  if (i < n) p[i] = 0u;
}

// ---------------- relu(thought)->bf16 from tagged-h buffer, padded to 128 rows ----------------
__global__ void thought_prep2_k(const ull* __restrict__ th, __hip_bfloat16* __restrict__ outp) {
  int row = blockIdx.x;  // 0..127 ; 128 threads, 4 elems each
  const int c = threadIdx.x << 2;
  float4 v = {0.f, 0.f, 0.f, 0.f};
  if (row < Bb) {
    const ull* p = th + (size_t)row * Hh + c;
    v.x = __uint_as_float((unsigned)p[0]);
    v.y = __uint_as_float((unsigned)p[1]);
    v.z = __uint_as_float((unsigned)p[2]);
    v.w = __uint_as_float((unsigned)p[3]);
  }
  v.x = fmaxf(v.x, 0.f); v.y = fmaxf(v.y, 0.f);
  v.z = fmaxf(v.z, 0.f); v.w = fmaxf(v.w, 0.f);
  union { __hip_bfloat16 h[4]; uint2 u; } o;
  o.h[0] = __float2bfloat16(v.x);
  o.h[1] = __float2bfloat16(v.y);
  o.h[2] = __float2bfloat16(v.z);
  o.h[3] = __float2bfloat16(v.w);
  ((uint2*)(outp + (size_t)row * Hh))[threadIdx.x] = o.u;
}

// ---------------- bf16 MFMA GEMM: C = A[M,K]*B[N,K]^T (+bias1[n]) (+bias2[(m>>6)*1536+n])
// 1D grid (XCD-chunked bijective swizzle). tile 128x128, BK=64, 4 waves;
// global_load_lds width-16 staging (m97 structure).
// partials mode (partials!=nullptr): emit per-(row, 64-col half-tile) {rowmax, sumexp}
// to partials[row*500 + seg] (one writer per slot) AND write logits as bf16 to Cbf
// (halves the HBM write volume); else write f32 to C.
__global__ __launch_bounds__(256) void gemm_bf16_k(
    const __hip_bfloat16* __restrict__ A,
    const __hip_bfloat16* __restrict__ B,
    float* __restrict__ C,
    __hip_bfloat16* __restrict__ Cbf,
    int lda, int ldb, int ldc, int K,
    const float* __restrict__ bias1,
    const float* __restrict__ bias2,
    float2* __restrict__ partials,
    int ntm) {
  __shared__ __align__(16) char smem[32768];
  auto sA = (__hip_bfloat16(*)[64])smem;            // [128][64]
  auto sB = (__hip_bfloat16(*)[64])(smem + 16384);  // [128][64]

  // bijective XCD-chunked swizzle (works for any nwg)
  const unsigned nwg = gridDim.x, gid = blockIdx.x;
  const unsigned q = nwg >> 3, r8 = nwg & 7, xc = gid & 7, jj = gid >> 3;
  const unsigned wg = (xc < r8 ? xc * (q + 1) : r8 * (q + 1) + (xc - r8) * q) + jj;
  const int m0 = (int)(wg % (unsigned)ntm) << 7;
  const int n0 = (int)(wg / (unsigned)ntm) << 7;

  const int tid = threadIdx.x;
  const int l = tid & 63, w = tid >> 6;
  const int wm = (w & 1) << 6, wn = (w >> 1) << 6;
  const int lr = l & 15;                 // fragment row within 16
  const int lk = (l >> 4) << 3;          // k-offset within 32
  const int lrow = (w << 3) + (l >> 3);  // staging row within 32-group
  const int lcol = (l & 7) << 3;         // staging col (elems), 8 bf16 = 16B

  f32x4 acc[4][4];
  #pragma unroll
  for (int i = 0; i < 4; ++i) {
    #pragma unroll
    for (int j = 0; j < 4; ++j) acc[i][j] = {0.f, 0.f, 0.f, 0.f};
  }

  for (int k0 = 0; k0 < K; k0 += 64) {
    #pragma unroll
    for (int rr = 0; rr < 4; ++rr) {
      gl_lds16(A + (size_t)(m0 + (rr << 5) + lrow) * lda + k0 + lcol, &sA[(rr << 5) + (w << 3)][0]);
      gl_lds16(B + (size_t)(n0 + (rr << 5) + lrow) * ldb + k0 + lcol, &sB[(rr << 5) + (w << 3)][0]);
    }
    __syncthreads();
    #pragma unroll
    for (int kk = 0; kk < 64; kk += 32) {
      short8 aF[4], bF[4];
      #pragma unroll
      for (int ms = 0; ms < 4; ++ms) aF[ms] = *(const short8*)(&sA[wm + (ms << 4) + lr][kk + lk]);
      #pragma unroll
      for (int ns = 0; ns < 4; ++ns) bF[ns] = *(const short8*)(&sB[wn + (ns << 4) + lr][kk + lk]);
      #pragma unroll
      for (int ms = 0; ms < 4; ++ms) {
        #pragma unroll
        for (int ns = 0; ns < 4; ++ns) {
          acc[ms][ns] = __builtin_amdgcn_mfma_f32_16x16x32_bf16(aF[ms], bF[ns], acc[ms][ns], 0, 0, 0);
        }
      }
    }
    __syncthreads();
  }

  // ---- epilogue: LDS round-trip per 16-row group, coalesced stores ----
  float* sg = (float*)smem + w * 1088;      // 16 rows * 68 f32 per wave
  const int r2w = l >> 4;
  const int cw = l & 15;
  const int rbase = r2w << 2;
  #pragma unroll
  for (int ms = 0; ms < 4; ++ms) {
    #pragma unroll
    for (int ns = 0; ns < 4; ++ns) {
      #pragma unroll
      for (int r = 0; r < 4; ++r) sg[(rbase + r) * 68 + (ns << 4) + lr] = acc[ms][ns][r];
    }
    #pragma unroll
    for (int qq = 0; qq < 4; ++qq) {
      const int srow2 = (qq << 2) + r2w;
      float4 v = *(const float4*)&sg[srow2 * 68 + (cw << 2)];
      const int row = m0 + wm + (ms << 4) + srow2;
      const int col = n0 + wn + (cw << 2);
      if (bias1) {
        float4 b1 = *(const float4*)&bias1[col];
        v.x += b1.x; v.y += b1.y; v.z += b1.z; v.w += b1.w;
      }
      if (bias2) {
        float4 b2 = *(const float4*)&bias2[(size_t)(row >> 6) * G3 + col];
        v.x += b2.x; v.y += b2.y; v.z += b2.z; v.w += b2.w;
      }
      if (partials) {
        float m4 = fmaxf(fmaxf(v.x, v.y), fmaxf(v.z, v.w));
        #pragma unroll
        for (int hop = 1; hop < 16; hop <<= 1) m4 = fmaxf(m4, __shfl_xor(m4, hop));
        float e = __expf(v.x - m4) + __expf(v.y - m4) + __expf(v.z - m4) + __expf(v.w - m4);
        #pragma unroll
        for (int hop = 1; hop < 16; hop <<= 1) e += __shfl_xor(e, hop);
        if (cw == 0) partials[(size_t)row * 500 + ((n0 >> 6) + (wn >> 6))] = make_float2(m4, e);
        union { __hip_bfloat16 h[4]; uint2 u; } o;
        o.h[0] = __float2bfloat16(v.x);
        o.h[1] = __float2bfloat16(v.y);
        o.h[2] = __float2bfloat16(v.z);
        o.h[3] = __float2bfloat16(v.w);
        *(uint2*)&Cbf[(size_t)row * ldc + col] = o.u;
      } else {
        *(float4*)&C[(size_t)row * ldc + col] = v;
      }
    }
  }
}

// ---------------- persistent GRU v6: tagged exchange + shuffle reduction (1 barrier/step) ----------------
// grid (16 i-slices of 32, 8 batch-groups of 4) = 128 blocks x 512 thr (co-resident).
// Thread map: il = tid>>4 (output i within slice), kc = tid&15 (k-chunk of 32).
// The 16 kc-partials for one output live in ONE 16-lane shuffle group -> cross-kc
// reduction is 4 __shfl_xor hops; sRed/B1/B2 deleted. sH double-buffered by step
// parity; the single B0 barrier's 2-deep semantics protect both parities.
// Poll: all 4 tag-words loaded in parallel (one LLC latency), retry together.
// Sync protocol (tagged-value, relaxed agent atomics) identical to proven v5.
__global__ __launch_bounds__(512, 1) void gru_seq6_k(
    const float* __restrict__ xp,        // [2048,1536], row m=b*64+t, includes bih(+tp)
    const uint2* __restrict__ whhB,      // [512k][512i] packed bf16
    const float* __restrict__ bhh,       // [1536]
    ull* __restrict__ hTag,              // [2][32][512] tagged h, zeroed before launch
    __hip_bfloat16* __restrict__ dec_out)// null or [2048,512]
{
  const int tid = threadIdx.x;
  const int slice = blockIdx.x;             // 0..15
  const int i0 = slice << 5;
  const int bg = blockIdx.y;
  const int il = tid >> 4;                  // 0..31
  const int kc = tid & 15;                  // 0..15
  const int kb0 = kc << 5;
  __shared__ __align__(16) float sH[2][2048];

  // ---- step-invariant weights -> 96 VGPRs ----
  float wrF[32], wzF[32], wnF[32];
  {
    const uint2* wp = whhB + i0 + il;
    #pragma unroll
    for (int k4 = 0; k4 < 8; ++k4) {
      #pragma unroll
      for (int j = 0; j < 4; ++j) {
        const int idx = (k4 << 2) + j;
        uint2 wv = wp[(size_t)(kb0 + idx) << 9];
        wrF[idx] = __uint_as_float(wv.x << 16);
        wzF[idx] = __uint_as_float(wv.x & 0xffff0000u);
        wnF[idx] = __uint_as_float(wv.y << 16);
      }
    }
  }

  const bool isTail = (kc == 0);
  const int gi = i0 + il;
  float bh_r = 0.f, bh_z = 0.f, bh_n = 0.f;
  float xpr[4], xpz[4], xpn[4];
  if (isTail) {
    bh_r = bhh[gi]; bh_z = bhh[512 + gi]; bh_n = bhh[1024 + gi];
    #pragma unroll
    for (int b = 0; b < 4; ++b) {
      const size_t m = (size_t)((bg << 2) + b) * Tt;  // t = 0
      xpr[b] = xp[m * G3 + gi];
      xpz[b] = xp[m * G3 + 512 + gi];
      xpn[b] = xp[m * G3 + 1024 + gi];
    }
  }

  #pragma unroll 1
  for (int t = 0; t < Tt; ++t) {
    // ---- poll + load h(t): 4 parallel tag-word loads, parity t ----
    {
      const ull* hb = hTag + ((size_t)(t & 1) << 14) + ((size_t)bg << 11);
      const unsigned tt = (unsigned)t;
      ull v0, v1, v2, v3;
      for (;;) {
        v0 = __hip_atomic_load(hb + tid,        __ATOMIC_RELAXED, __HIP_MEMORY_SCOPE_AGENT);
        v1 = __hip_atomic_load(hb + 512 + tid,  __ATOMIC_RELAXED, __HIP_MEMORY_SCOPE_AGENT);
        v2 = __hip_atomic_load(hb + 1024 + tid, __ATOMIC_RELAXED, __HIP_MEMORY_SCOPE_AGENT);
        v3 = __hip_atomic_load(hb + 1536 + tid, __ATOMIC_RELAXED, __HIP_MEMORY_SCOPE_AGENT);
        if ((unsigned)(v0 >> 32) == tt && (unsigned)(v1 >> 32) == tt &&
            (unsigned)(v2 >> 32) == tt && (unsigned)(v3 >> 32) == tt) break;
        __builtin_amdgcn_s_sleep(1);
      }
      float* shw = sH[t & 1];
      shw[tid]        = __uint_as_float((unsigned)v0);
      shw[512 + tid]  = __uint_as_float((unsigned)v1);
      shw[1024 + tid] = __uint_as_float((unsigned)v2);
      shw[1536 + tid] = __uint_as_float((unsigned)v3);
    }
    __syncthreads();   // B0: sH(t) complete (only barrier per step)

    float a[12];
    #pragma unroll
    for (int v = 0; v < 12; ++v) a[v] = 0.f;
    const float* sh = sH[t & 1];
    #pragma unroll
    for (int k4 = 0; k4 < 8; ++k4) {
      const int kb = kb0 + (k4 << 2);
      float4 hv0 = *(const float4*)&sh[kb];
      float4 hv1 = *(const float4*)&sh[512 + kb];
      float4 hv2 = *(const float4*)&sh[1024 + kb];
      float4 hv3 = *(const float4*)&sh[1536 + kb];
      const float* h0p = (const float*)&hv0;
      const float* h1p = (const float*)&hv1;
      const float* h2p = (const float*)&hv2;
      const float* h3p = (const float*)&hv3;
      #pragma unroll
      for (int j = 0; j < 4; ++j) {
        const int idx = (k4 << 2) + j;
        const float wr = wrF[idx], wz = wzF[idx], wn = wnF[idx];
        a[0]  = fmaf(wr, h0p[j], a[0]);  a[1]  = fmaf(wz, h0p[j], a[1]);  a[2]  = fmaf(wn, h0p[j], a[2]);
        a[3]  = fmaf(wr, h1p[j], a[3]);  a[4]  = fmaf(wz, h1p[j], a[4]);  a[5]  = fmaf(wn, h1p[j], a[5]);
        a[6]  = fmaf(wr, h2p[j], a[6]);  a[7]  = fmaf(wz, h2p[j], a[7]);  a[8]  = fmaf(wn, h2p[j], a[8]);
        a[9]  = fmaf(wr, h3p[j], a[9]);  a[10] = fmaf(wz, h3p[j], a[10]); a[11] = fmaf(wn, h3p[j], a[11]);
      }
    }
    // cross-kc reduction: butterfly over the 16-lane group
    #pragma unroll
    for (int off = 8; off >= 1; off >>= 1) {
      #pragma unroll
      for (int v = 0; v < 12; ++v) a[v] += __shfl_xor(a[v], off, 16);
    }

    if (isTail) {
      #pragma unroll
      for (int b = 0; b < 4; ++b) {
        const int bb = (bg << 2) + b;
        const float hr = a[b * 3 + 0] + bh_r;
        const float hz = a[b * 3 + 1] + bh_z;
        const float hn = a[b * 3 + 2] + bh_n;
        const float rg = 1.f / (1.f + __expf(-(xpr[b] + hr)));
        const float zg = 1.f / (1.f + __expf(-(xpz[b] + hz)));
        const float ng = tanhf(xpn[b] + rg * hn);
        const float hnew = (1.f - zg) * ng + zg * sh[(b << 9) + gi];
        ull* dst = hTag + ((size_t)((t + 1) & 1) << 14) + ((size_t)bb << 9) + gi;
        __hip_atomic_store(dst, ((ull)(unsigned)(t + 1) << 32) | (ull)__float_as_uint(hnew),
                           __ATOMIC_RELAXED, __HIP_MEMORY_SCOPE_AGENT);
        if (dec_out) dec_out[((size_t)(bb * Tt + t) << 9) + gi] = __float2bfloat16(hnew);
      }
      if (t + 1 < Tt) {   // prefetch next step's xp (off critical path)
        #pragma unroll
        for (int b = 0; b < 4; ++b) {
          const size_t m = (size_t)((bg << 2) + b) * Tt + (t + 1);
          xpr[b] = xp[m * G3 + gi];
          xpz[b] = xp[m * G3 + 512 + gi];
          xpn[b] = xp[m * G3 + 1024 + gi];
        }
      }
    }
    // no trailing barrier: sH double-buffered; next B0 provides 2-deep safety
  }
}

// ---------------- final log-softmax (f32 logits path): reduce partials, subtract in place ----------------
__global__ __launch_bounds__(256) void lsm_final_k(float* __restrict__ X,
                                                   const float2* __restrict__ P) {
  const int row = blockIdx.x;
  const int tid = threadIdx.x;
  float m = -3.4e38f, s = 0.f;
  for (int j = tid; j < 500; j += 256) {
    float2 p = P[(size_t)row * 500 + j];
    if (p.x > m) { s = s * __expf(m - p.x) + p.y; m = p.x; }
    else         { s += p.y * __expf(p.x - m); }
  }
  #pragma unroll
  for (int off2 = 32; off2 > 0; off2 >>= 1) {
    float mo = __shfl_down(m, off2);
    float so = __shfl_down(s, off2);
    float M = fmaxf(m, mo);
    s = s * __expf(m - M) + so * __expf(mo - M);
    m = M;
  }
  __shared__ float sm[4], ss[4];
  if ((tid & 63) == 0) { sm[tid >> 6] = m; ss[tid >> 6] = s; }
  __syncthreads();
  const float M4 = fmaxf(fmaxf(sm[0], sm[1]), fmaxf(sm[2], sm[3]));
  const float S = ss[0] * __expf(sm[0] - M4) + ss[1] * __expf(sm[1] - M4) +
                  ss[2] * __expf(sm[2] - M4) + ss[3] * __expf(sm[3] - M4);
  const float c = M4 + __logf(S);
  float4* p4 = (float4*)(X + (size_t)row * Vv);
  for (int j = tid; j < Vv / 4; j += 256) {
    float4 v = p4[j];
    v.x -= c; v.y -= c; v.z -= c; v.w -= c;
    p4[j] = v;
  }
}

// ---------------- final log-softmax (bf16 logits path): read bf16, write f32 d_out ----------------
__global__ __launch_bounds__(256) void lsm_final2_k(float* __restrict__ X,
                                                    const __hip_bfloat16* __restrict__ L,
                                                    const float2* __restrict__ P) {
  const int row = blockIdx.x;
  const int tid = threadIdx.x;
  float m = -3.4e38f, s = 0.f;
  for (int j = tid; j < 500; j += 256) {
    float2 p = P[(size_t)row * 500 + j];
    if (p.x > m) { s = s * __expf(m - p.x) + p.y; m = p.x; }
    else         { s += p.y * __expf(p.x - m); }
  }
  #pragma unroll
  for (int off2 = 32; off2 > 0; off2 >>= 1) {
    float mo = __shfl_down(m, off2);
    float so = __shfl_down(s, off2);
    float M = fmaxf(m, mo);
    s = s * __expf(m - M) + so * __expf(mo - M);
    m = M;
  }
  __shared__ float sm[4], ss[4];
  if ((tid & 63) == 0) { sm[tid >> 6] = m; ss[tid >> 6] = s; }
  __syncthreads();
  const float M4 = fmaxf(fmaxf(sm[0], sm[1]), fmaxf(sm[2], sm[3]));
  const float S = ss[0] * __expf(sm[0] - M4) + ss[1] * __expf(sm[1] - M4) +
                  ss[2] * __expf(sm[2] - M4) + ss[3] * __expf(sm[3] - M4);
  const float c = M4 + __logf(S);
  const short8* p8 = (const short8*)(L + (size_t)row * Vv);
  float4* o4 = (float4*)(X + (size_t)row * Vv);
  for (int j = tid; j < Vv / 8; j += 256) {
    short8 sv = p8[j];
    float4 a, b;
    a.x = __uint_as_float(((unsigned)(unsigned short)sv[0]) << 16) - c;
    a.y = __uint_as_float(((unsigned)(unsigned short)sv[1]) << 16) - c;
    a.z = __uint_as_float(((unsigned)(unsigned short)sv[2]) << 16) - c;
    a.w = __uint_as_float(((unsigned)(unsigned short)sv[3]) << 16) - c;
    b.x = __uint_as_float(((unsigned)(unsigned short)sv[4]) << 16) - c;
    b.y = __uint_as_float(((unsigned)(unsigned short)sv[5]) << 16) - c;
    b.z = __uint_as_float(((unsigned)(unsigned short)sv[6]) << 16) - c;
    b.w = __uint_as_float(((unsigned)(unsigned short)sv[7]) << 16) - c;
    o4[(j << 1)] = a;
    o4[(j << 1) + 1] = b;
  }
}

}  // namespace

extern "C" void kernel_launch(void* const* d_in, const int* in_sizes, int n_in,
                              void* d_out, int out_size, void* d_ws, size_t ws_size,
                              hipStream_t stream) {
  (void)in_sizes; (void)n_in; (void)out_size;
  const int*   in_seq  = (const int*)d_in[0];
  const int*   tgt_seq = (const int*)d_in[1];
  const float* enc_emb = (const float*)d_in[2];
  const float* enc_Wih = (const float*)d_in[3];
  const float* enc_Whh = (const float*)d_in[4];
  const float* enc_bih = (const float*)d_in[5];
  const float* enc_bhh = (const float*)d_in[6];
  const float* dec_emb = (const float*)d_in[7];
  const float* dec_Wih = (const float*)d_in[8];
  const float* dec_Whh = (const float*)d_in[9];
  const float* dec_bih = (const float*)d_in[10];
  const float* dec_bhh = (const float*)d_in[11];
  const float* out_W   = (const float*)d_in[12];
  const float* out_b   = (const float*)d_in[13];
  float* out = (float*)d_out;

  char* ws = (char*)d_ws;
  size_t off = 0;
  auto alloc = [&](size_t bytes) -> void* {
    void* p = (void*)(ws + off);
    off += (bytes + 255) & ~(size_t)255;
    return p;
  };
  uint2* whhB_e            = (uint2*)alloc((size_t)512 * 512 * 8);   // 2MB packed bf16
  uint2* whhB_d            = (uint2*)alloc((size_t)512 * 512 * 8);
  __hip_bfloat16* encWih_bf = (__hip_bfloat16*)alloc((size_t)1536 * 512 * 2);
  __hip_bfloat16* decWih_bf = (__hip_bfloat16*)alloc((size_t)1536 * 1024 * 2);
  __hip_bfloat16* outW_bf   = (__hip_bfloat16*)alloc((size_t)32000 * 512 * 2);
  __hip_bfloat16* encX_bf   = (__hip_bfloat16*)alloc((size_t)2048 * 512 * 2);
  __hip_bfloat16* decX_bf   = (__hip_bfloat16*)alloc((size_t)2048 * 512 * 2);
  float* enc_xp            = (float*)alloc((size_t)2048 * 1536 * 4);
  float* dec_xp            = (float*)alloc((size_t)2048 * 1536 * 4);
  float* tp                = (float*)alloc((size_t)128 * 1536 * 4);
  __hip_bfloat16* th_bf     = (__hip_bfloat16*)alloc((size_t)128 * 512 * 2);
  ull* hTag                = (ull*)alloc((size_t)2 * 32 * 512 * 8);  // 256KB tagged h
  __hip_bfloat16* decOut_bf = (__hip_bfloat16*)alloc((size_t)2048 * 512 * 2);
  float2* partials         = (float2*)alloc((size_t)2048 * 500 * 8); // 8.2MB softmax stats
  __hip_bfloat16* logitsBf  = (__hip_bfloat16*)alloc((size_t)2048 * Vv * 2);  // 131MB (optional)
  const bool bfLogits = (off <= ws_size);

  // --- weight preprocessing ---
  cvt_bf16_k<<<768, 256, 0, stream>>>(enc_Wih, encWih_bf, 1536 * 512 / 4);
  cvt_bf16_k<<<1536, 256, 0, stream>>>(dec_Wih, decWih_bf, 1536 * 1024 / 4);
  cvt_bf16_k<<<16000, 256, 0, stream>>>(out_W, outW_bf, 32000 * 512 / 4);
  pack_whh_bf_k<<<dim3(8, 16), 256, 0, stream>>>(enc_Whh, whhB_e);
  pack_whh_bf_k<<<dim3(8, 16), 256, 0, stream>>>(dec_Whh, whhB_d);

  // --- embeddings ---
  embed_k<<<2048, 128, 0, stream>>>(in_seq, enc_emb, encX_bf, 0);
  embed_k<<<2048, 128, 0, stream>>>(tgt_seq, dec_emb, decX_bf, 1);

  // --- encoder xp = enc_x @ Wih^T + bih : [2048,1536] ---
  gemm_bf16_k<<<192, 256, 0, stream>>>(encX_bf, encWih_bf, enc_xp, nullptr,
                                       512, 512, G3, 512, enc_bih, nullptr, nullptr, 16);

  // --- encoder GRU: persistent, 1 launch (hTag zeroed => valid h(0)=0 tag 0) ---
  zero_k<<<128, 256, 0, stream>>>((unsigned*)hTag, 2 * 32 * 512 * 2);
  gru_seq6_k<<<dim3(16, 8), 512, 0, stream>>>(enc_xp, whhB_e, enc_bhh, hTag, nullptr);
  // h(64) tag 64 lives in buffer 0 (even parity)

  // --- tp = relu(thought) @ dec_Wih[:,512:]^T + dec_bih : [128(pad),1536] ---
  thought_prep2_k<<<128, 128, 0, stream>>>(hTag, th_bf);
  gemm_bf16_k<<<12, 256, 0, stream>>>(th_bf, decWih_bf + 512, tp, nullptr,
                                      512, 1024, G3, 512, dec_bih, nullptr, nullptr, 1);

  // --- decoder xp = relu(dec_x) @ dec_Wih[:,:512]^T + tp[b] : [2048,1536] ---
  gemm_bf16_k<<<192, 256, 0, stream>>>(decX_bf, decWih_bf, dec_xp, nullptr,
                                       512, 1024, G3, 512, nullptr, tp, nullptr, 16);

  // --- decoder GRU: persistent, 1 launch (re-zero tags!) ---
  zero_k<<<128, 256, 0, stream>>>((unsigned*)hTag, 2 * 32 * 512 * 2);
  gru_seq6_k<<<dim3(16, 8), 512, 0, stream>>>(dec_xp, whhB_d, dec_bhh, hTag, decOut_bf);

  if (bfLogits) {
    // --- logits (bf16) + fused softmax stats; final reads bf16, writes f32 d_out ---
    gemm_bf16_k<<<4000, 256, 0, stream>>>(decOut_bf, outW_bf, nullptr, logitsBf,
                                          512, 512, Vv, 512, out_b, nullptr, partials, 16);
    lsm_final2_k<<<2048, 256, 0, stream>>>(out, logitsBf, partials);
  } else {
    // --- fallback: f32 logits in d_out + in-place subtract (round-8 proven path) ---
    gemm_bf16_k<<<4000, 256, 0, stream>>>(decOut_bf, outW_bf, out, nullptr,
                                          512, 512, Vv, 512, out_b, nullptr, partials, 16);
    lsm_final_k<<<2048, 256, 0, stream>>>(out, partials);
  }
}

// Round 10
// 995.548 us; speedup vs baseline: 1.2999x; 1.2999x over previous
//
#include <hip/hip_runtime.h>
#include <hip/hip_bf16.h>
#include <cstdint>
#include <cstddef>

namespace {

constexpr int Hh = 512;
constexpr int G3 = 1536;   // 3*H
constexpr int Bb = 32;
constexpr int Tt = 64;
constexpr int Vv = 32000;

typedef __attribute__((ext_vector_type(8))) short short8;
typedef __attribute__((ext_vector_type(4))) float f32x4;
typedef unsigned long long ull;

__device__ __forceinline__ unsigned bf16bits(float f) {
  union { __hip_bfloat16 h; unsigned short u; } c;
  c.h = __float2bfloat16(f);
  return (unsigned)c.u;
}

// async global->LDS, 16B per lane; LDS dest = wave-uniform base + lane*16
__device__ __forceinline__ void gl_lds16(const void* g, void* l) {
  __builtin_amdgcn_global_load_lds(
      (const __attribute__((address_space(1))) unsigned int*)g,
      (__attribute__((address_space(3))) unsigned int*)l, 16, 0, 0);
}

// ---------------- f32 -> bf16 convert (vectorized) ----------------
__global__ void cvt_bf16_k(const float* __restrict__ src, __hip_bfloat16* __restrict__ dst, int n4) {
  int i = blockIdx.x * blockDim.x + threadIdx.x;
  if (i >= n4) return;
  float4 v = ((const float4*)src)[i];
  union { __hip_bfloat16 h[4]; uint2 u; } o;
  o.h[0] = __float2bfloat16(v.x);
  o.h[1] = __float2bfloat16(v.y);
  o.h[2] = __float2bfloat16(v.z);
  o.h[3] = __float2bfloat16(v.w);
  ((uint2*)dst)[i] = o.u;
}

// ---------------- pack Whh[1536][512] -> P[k][i] = {bf16 r, bf16 z | bf16 n, 0} uint2, 2MB ----------------
__global__ void pack_whh_bf_k(const float* __restrict__ Whh, uint2* __restrict__ P) {
  __shared__ float tw[3][32][65];
  const int k0 = blockIdx.x * 64, i0 = blockIdx.y * 32;
  const int t = threadIdx.x;               // 256
  const int kk = t & 63, r4 = t >> 6;
  for (int ri = r4; ri < 96; ri += 4) {
    const int g = ri >> 5, ii = ri & 31;
    tw[g][ii][kk] = Whh[(size_t)(g * 512 + i0 + ii) * 512 + k0 + kk];
  }
  __syncthreads();
  const int ii = t & 31, kq = t >> 5;
  for (int k2 = kq; k2 < 64; k2 += 8) {
    unsigned rb = bf16bits(tw[0][ii][k2]);
    unsigned zb = bf16bits(tw[1][ii][k2]);
    unsigned nb = bf16bits(tw[2][ii][k2]);
    P[(size_t)(k0 + k2) * 512 + i0 + ii] = make_uint2((zb << 16) | rb, nb);
  }
}

// ---------------- embedding gather (optionally relu) -> bf16 [2048][512] ----------------
__global__ void embed_k(const int* __restrict__ idx, const float* __restrict__ emb,
                        __hip_bfloat16* __restrict__ outp, int do_relu) {
  int row = blockIdx.x;            // 0..2047 (= b*64+t)
  int r = idx[row];
  float4 v = ((const float4*)(emb + (size_t)r * Hh))[threadIdx.x];  // 128 thr * 4
  if (do_relu) {
    v.x = fmaxf(v.x, 0.f); v.y = fmaxf(v.y, 0.f);
    v.z = fmaxf(v.z, 0.f); v.w = fmaxf(v.w, 0.f);
  }
  union { __hip_bfloat16 h[4]; uint2 u; } o;
  o.h[0] = __float2bfloat16(v.x);
  o.h[1] = __float2bfloat16(v.y);
  o.h[2] = __float2bfloat16(v.z);
  o.h[3] = __float2bfloat16(v.w);
  ((uint2*)(outp + (size_t)row * Hh))[threadIdx.x] = o.u;
}

// ---------------- zero u32 ----------------
__global__ void zero_k(unsigned* __restrict__ p, int n) {
  int i = blockIdx.x * blockDim.x + threadIdx.x;
  if (i < n) p[i] = 0u;
}

// ---------------- relu(thought)->bf16 from tagged-h buffer, padded to 128 rows ----------------
__global__ void thought_prep2_k(const ull* __restrict__ th, __hip_bfloat16* __restrict__ outp) {
  int row = blockIdx.x;  // 0..127 ; 128 threads, 4 elems each
  const int c = threadIdx.x << 2;
  float4 v = {0.f, 0.f, 0.f, 0.f};
  if (row < Bb) {
    const ull* p = th + (size_t)row * Hh + c;
    v.x = __uint_as_float((unsigned)p[0]);
    v.y = __uint_as_float((unsigned)p[1]);
    v.z = __uint_as_float((unsigned)p[2]);
    v.w = __uint_as_float((unsigned)p[3]);
  }
  v.x = fmaxf(v.x, 0.f); v.y = fmaxf(v.y, 0.f);
  v.z = fmaxf(v.z, 0.f); v.w = fmaxf(v.w, 0.f);
  union { __hip_bfloat16 h[4]; uint2 u; } o;
  o.h[0] = __float2bfloat16(v.x);
  o.h[1] = __float2bfloat16(v.y);
  o.h[2] = __float2bfloat16(v.z);
  o.h[3] = __float2bfloat16(v.w);
  ((uint2*)(outp + (size_t)row * Hh))[threadIdx.x] = o.u;
}

// ---------------- bf16 MFMA GEMM: C = A[M,K]*B[N,K]^T (+bias1[n]) (+bias2[(m>>6)*1536+n])
// 1D grid (XCD-chunked bijective swizzle). tile 128x128, BK=64, 4 waves;
// global_load_lds width-16 staging (m97 structure).
// partials mode (partials!=nullptr): emit per-(row, 64-col half-tile) {rowmax, sumexp}
// to partials[row*500 + seg] (one writer per slot) AND write logits as bf16 to Cbf
// (halves the HBM write volume); else write f32 to C.
__global__ __launch_bounds__(256) void gemm_bf16_k(
    const __hip_bfloat16* __restrict__ A,
    const __hip_bfloat16* __restrict__ B,
    float* __restrict__ C,
    __hip_bfloat16* __restrict__ Cbf,
    int lda, int ldb, int ldc, int K,
    const float* __restrict__ bias1,
    const float* __restrict__ bias2,
    float2* __restrict__ partials,
    int ntm) {
  __shared__ __align__(16) char smem[32768];
  auto sA = (__hip_bfloat16(*)[64])smem;            // [128][64]
  auto sB = (__hip_bfloat16(*)[64])(smem + 16384);  // [128][64]

  // bijective XCD-chunked swizzle (works for any nwg)
  const unsigned nwg = gridDim.x, gid = blockIdx.x;
  const unsigned q = nwg >> 3, r8 = nwg & 7, xc = gid & 7, jj = gid >> 3;
  const unsigned wg = (xc < r8 ? xc * (q + 1) : r8 * (q + 1) + (xc - r8) * q) + jj;
  const int m0 = (int)(wg % (unsigned)ntm) << 7;
  const int n0 = (int)(wg / (unsigned)ntm) << 7;

  const int tid = threadIdx.x;
  const int l = tid & 63, w = tid >> 6;
  const int wm = (w & 1) << 6, wn = (w >> 1) << 6;
  const int lr = l & 15;                 // fragment row within 16
  const int lk = (l >> 4) << 3;          // k-offset within 32
  const int lrow = (w << 3) + (l >> 3);  // staging row within 32-group
  const int lcol = (l & 7) << 3;         // staging col (elems), 8 bf16 = 16B

  f32x4 acc[4][4];
  #pragma unroll
  for (int i = 0; i < 4; ++i) {
    #pragma unroll
    for (int j = 0; j < 4; ++j) acc[i][j] = {0.f, 0.f, 0.f, 0.f};
  }

  for (int k0 = 0; k0 < K; k0 += 64) {
    #pragma unroll
    for (int rr = 0; rr < 4; ++rr) {
      gl_lds16(A + (size_t)(m0 + (rr << 5) + lrow) * lda + k0 + lcol, &sA[(rr << 5) + (w << 3)][0]);
      gl_lds16(B + (size_t)(n0 + (rr << 5) + lrow) * ldb + k0 + lcol, &sB[(rr << 5) + (w << 3)][0]);
    }
    __syncthreads();
    #pragma unroll
    for (int kk = 0; kk < 64; kk += 32) {
      short8 aF[4], bF[4];
      #pragma unroll
      for (int ms = 0; ms < 4; ++ms) aF[ms] = *(const short8*)(&sA[wm + (ms << 4) + lr][kk + lk]);
      #pragma unroll
      for (int ns = 0; ns < 4; ++ns) bF[ns] = *(const short8*)(&sB[wn + (ns << 4) + lr][kk + lk]);
      #pragma unroll
      for (int ms = 0; ms < 4; ++ms) {
        #pragma unroll
        for (int ns = 0; ns < 4; ++ns) {
          acc[ms][ns] = __builtin_amdgcn_mfma_f32_16x16x32_bf16(aF[ms], bF[ns], acc[ms][ns], 0, 0, 0);
        }
      }
    }
    __syncthreads();
  }

  // ---- epilogue: LDS round-trip per 16-row group, coalesced stores ----
  float* sg = (float*)smem + w * 1088;      // 16 rows * 68 f32 per wave
  const int r2w = l >> 4;
  const int cw = l & 15;
  const int rbase = r2w << 2;
  #pragma unroll
  for (int ms = 0; ms < 4; ++ms) {
    #pragma unroll
    for (int ns = 0; ns < 4; ++ns) {
      #pragma unroll
      for (int r = 0; r < 4; ++r) sg[(rbase + r) * 68 + (ns << 4) + lr] = acc[ms][ns][r];
    }
    #pragma unroll
    for (int qq = 0; qq < 4; ++qq) {
      const int srow2 = (qq << 2) + r2w;
      float4 v = *(const float4*)&sg[srow2 * 68 + (cw << 2)];
      const int row = m0 + wm + (ms << 4) + srow2;
      const int col = n0 + wn + (cw << 2);
      if (bias1) {
        float4 b1 = *(const float4*)&bias1[col];
        v.x += b1.x; v.y += b1.y; v.z += b1.z; v.w += b1.w;
      }
      if (bias2) {
        float4 b2 = *(const float4*)&bias2[(size_t)(row >> 6) * G3 + col];
        v.x += b2.x; v.y += b2.y; v.z += b2.z; v.w += b2.w;
      }
      if (partials) {
        float m4 = fmaxf(fmaxf(v.x, v.y), fmaxf(v.z, v.w));
        #pragma unroll
        for (int hop = 1; hop < 16; hop <<= 1) m4 = fmaxf(m4, __shfl_xor(m4, hop));
        float e = __expf(v.x - m4) + __expf(v.y - m4) + __expf(v.z - m4) + __expf(v.w - m4);
        #pragma unroll
        for (int hop = 1; hop < 16; hop <<= 1) e += __shfl_xor(e, hop);
        if (cw == 0) partials[(size_t)row * 500 + ((n0 >> 6) + (wn >> 6))] = make_float2(m4, e);
        union { __hip_bfloat16 h[4]; uint2 u; } o;
        o.h[0] = __float2bfloat16(v.x);
        o.h[1] = __float2bfloat16(v.y);
        o.h[2] = __float2bfloat16(v.z);
        o.h[3] = __float2bfloat16(v.w);
        *(uint2*)&Cbf[(size_t)row * ldc + col] = o.u;
      } else {
        *(float4*)&C[(size_t)row * ldc + col] = v;
      }
    }
  }
}

// ---------------- persistent GRU v7: v5 conflict-free body + parallel poll + sH dbuf ----------------
// grid (16 i-slices of 32, 8 batch-groups of 4) = 128 blocks x 512 thr (co-resident).
// Thread map (v5, PROVEN conflict-free): il = tid&31, kc = tid>>5 -> sH reads are
// uniform per half-wave (broadcast, 0 bank conflicts; v6's kc=tid&15 was a 16-way
// conflict, 5.9e7 counted). Cross-kc reduction via sRed (stride-13 pad, conflict-free).
// Improvements over v5: (1) all 4 tag-words polled in parallel (1 LLC latency, not 4);
// (2) sH double-buffered by step parity -> trailing barrier B2 dropped (2 barriers/step;
// sRed stays single-buffered: its t+1 writes occur post-B0(t+1), which the tail joins
// only after finishing its reads); (3) xp(t+1) prefetched into tail registers.
// Cross-block protocol (tagged-value, relaxed agent atomics) byte-identical to v5/v6.
__global__ __launch_bounds__(512, 1) void gru_seq7_k(
    const float* __restrict__ xp,        // [2048,1536], row m=b*64+t, includes bih(+tp)
    const uint2* __restrict__ whhB,      // [512k][512i] packed bf16
    const float* __restrict__ bhh,       // [1536]
    ull* __restrict__ hTag,              // [2][32][512] tagged h, FULLY zeroed before launch
    __hip_bfloat16* __restrict__ dec_out)// null or [2048,512]
{
  const int tid = threadIdx.x;
  const int slice = blockIdx.x;             // 0..15
  const int i0 = slice << 5;
  const int bg = blockIdx.y;
  const int il = tid & 31, kc = tid >> 5;   // 32 i x 16 k-chunks(32k each)
  const int kb0 = kc << 5;
  __shared__ __align__(16) float sH[2][2048];
  __shared__ float sRed[512 * 13];

  // ---- step-invariant weights -> 96 VGPRs ----
  float wrF[32], wzF[32], wnF[32];
  {
    const uint2* wp = whhB + i0 + il;
    #pragma unroll
    for (int k4 = 0; k4 < 8; ++k4) {
      #pragma unroll
      for (int j = 0; j < 4; ++j) {
        const int idx = (k4 << 2) + j;
        uint2 wv = wp[(size_t)(kb0 + idx) << 9];
        wrF[idx] = __uint_as_float(wv.x << 16);
        wzF[idx] = __uint_as_float(wv.x & 0xffff0000u);
        wnF[idx] = __uint_as_float(wv.y << 16);
      }
    }
  }

  // ---- tail precompute (tid<128: one (b, gi) each) ----
  float bh_r = 0.f, bh_z = 0.f, bh_n = 0.f, xr = 0.f, xz = 0.f, xn = 0.f;
  int gi = 0, bb = 0;
  if (tid < 128) {
    const int b = tid >> 5, i2 = tid & 31;
    gi = i0 + i2;
    bb = (bg << 2) + b;
    bh_r = bhh[gi]; bh_z = bhh[512 + gi]; bh_n = bhh[1024 + gi];
    const size_t m = (size_t)bb * Tt;  // t = 0
    xr = xp[m * G3 + gi];
    xz = xp[m * G3 + 512 + gi];
    xn = xp[m * G3 + 1024 + gi];
  }

  #pragma unroll 1
  for (int t = 0; t < Tt; ++t) {
    // ---- poll + load h(t): 4 parallel tag-word loads, buffer = t parity ----
    {
      const ull* hb = hTag + ((size_t)(t & 1) << 14) + ((size_t)bg << 11);
      const unsigned tt = (unsigned)t;
      ull v0, v1, v2, v3;
      for (;;) {
        v0 = __hip_atomic_load(hb + tid,        __ATOMIC_RELAXED, __HIP_MEMORY_SCOPE_AGENT);
        v1 = __hip_atomic_load(hb + 512 + tid,  __ATOMIC_RELAXED, __HIP_MEMORY_SCOPE_AGENT);
        v2 = __hip_atomic_load(hb + 1024 + tid, __ATOMIC_RELAXED, __HIP_MEMORY_SCOPE_AGENT);
        v3 = __hip_atomic_load(hb + 1536 + tid, __ATOMIC_RELAXED, __HIP_MEMORY_SCOPE_AGENT);
        if ((unsigned)(v0 >> 32) == tt && (unsigned)(v1 >> 32) == tt &&
            (unsigned)(v2 >> 32) == tt && (unsigned)(v3 >> 32) == tt) break;
        __builtin_amdgcn_s_sleep(1);
      }
      float* shw = sH[t & 1];
      shw[tid]        = __uint_as_float((unsigned)v0);
      shw[512 + tid]  = __uint_as_float((unsigned)v1);
      shw[1024 + tid] = __uint_as_float((unsigned)v2);
      shw[1536 + tid] = __uint_as_float((unsigned)v3);
    }
    __syncthreads();   // B0: sH(t) complete

    float a[12];
    #pragma unroll
    for (int v = 0; v < 12; ++v) a[v] = 0.f;
    const float* sh = sH[t & 1];
    #pragma unroll
    for (int k4 = 0; k4 < 8; ++k4) {
      const int kb = kb0 + (k4 << 2);
      float4 hv0 = *(const float4*)&sh[kb];
      float4 hv1 = *(const float4*)&sh[512 + kb];
      float4 hv2 = *(const float4*)&sh[1024 + kb];
      float4 hv3 = *(const float4*)&sh[1536 + kb];
      const float* h0p = (const float*)&hv0;
      const float* h1p = (const float*)&hv1;
      const float* h2p = (const float*)&hv2;
      const float* h3p = (const float*)&hv3;
      #pragma unroll
      for (int j = 0; j < 4; ++j) {
        const int idx = (k4 << 2) + j;
        const float wr = wrF[idx], wz = wzF[idx], wn = wnF[idx];
        a[0]  = fmaf(wr, h0p[j], a[0]);  a[1]  = fmaf(wz, h0p[j], a[1]);  a[2]  = fmaf(wn, h0p[j], a[2]);
        a[3]  = fmaf(wr, h1p[j], a[3]);  a[4]  = fmaf(wz, h1p[j], a[4]);  a[5]  = fmaf(wn, h1p[j], a[5]);
        a[6]  = fmaf(wr, h2p[j], a[6]);  a[7]  = fmaf(wz, h2p[j], a[7]);  a[8]  = fmaf(wn, h2p[j], a[8]);
        a[9]  = fmaf(wr, h3p[j], a[9]);  a[10] = fmaf(wz, h3p[j], a[10]); a[11] = fmaf(wn, h3p[j], a[11]);
      }
    }
    {
      float* red = &sRed[tid * 13];
      #pragma unroll
      for (int v = 0; v < 12; ++v) red[v] = a[v];
    }
    __syncthreads();   // B1: sRed complete

    if (tid < 128) {
      const int i2 = tid & 31, b = tid >> 5;
      float s0 = 0.f, s1 = 0.f, s2 = 0.f;
      #pragma unroll
      for (int kc2 = 0; kc2 < 16; ++kc2) {
        const float* rp = &sRed[(kc2 * 32 + i2) * 13 + b * 3];
        s0 += rp[0]; s1 += rp[1]; s2 += rp[2];
      }
      const float hr = s0 + bh_r;
      const float hz = s1 + bh_z;
      const float hn = s2 + bh_n;
      const float rg = 1.f / (1.f + __expf(-(xr + hr)));
      const float zg = 1.f / (1.f + __expf(-(xz + hz)));
      const float ng = tanhf(xn + rg * hn);
      const float hnew = (1.f - zg) * ng + zg * sh[(b << 9) + gi];
      // single 8B store carries value + readiness tag (t+1)
      ull* dst = hTag + ((size_t)((t + 1) & 1) << 14) + ((size_t)bb << 9) + gi;
      __hip_atomic_store(dst, ((ull)(unsigned)(t + 1) << 32) | (ull)__float_as_uint(hnew),
                         __ATOMIC_RELAXED, __HIP_MEMORY_SCOPE_AGENT);
      if (dec_out) dec_out[((size_t)(bb * Tt + t) << 9) + gi] = __float2bfloat16(hnew);
      if (t + 1 < Tt) {   // prefetch next step's xp (off critical path)
        const size_t m = (size_t)bb * Tt + (t + 1);
        xr = xp[m * G3 + gi];
        xz = xp[m * G3 + 512 + gi];
        xn = xp[m * G3 + 1024 + gi];
      }
    }
    // no B2: sH parity-buffered; sRed's next write is post-B0(t+1)
  }
}

// ---------------- final log-softmax (f32 logits path): reduce partials, subtract in place ----------------
__global__ __launch_bounds__(256) void lsm_final_k(float* __restrict__ X,
                                                   const float2* __restrict__ P) {
  const int row = blockIdx.x;
  const int tid = threadIdx.x;
  float m = -3.4e38f, s = 0.f;
  for (int j = tid; j < 500; j += 256) {
    float2 p = P[(size_t)row * 500 + j];
    if (p.x > m) { s = s * __expf(m - p.x) + p.y; m = p.x; }
    else         { s += p.y * __expf(p.x - m); }
  }
  #pragma unroll
  for (int off2 = 32; off2 > 0; off2 >>= 1) {
    float mo = __shfl_down(m, off2);
    float so = __shfl_down(s, off2);
    float M = fmaxf(m, mo);
    s = s * __expf(m - M) + so * __expf(mo - M);
    m = M;
  }
  __shared__ float sm[4], ss[4];
  if ((tid & 63) == 0) { sm[tid >> 6] = m; ss[tid >> 6] = s; }
  __syncthreads();
  const float M4 = fmaxf(fmaxf(sm[0], sm[1]), fmaxf(sm[2], sm[3]));
  const float S = ss[0] * __expf(sm[0] - M4) + ss[1] * __expf(sm[1] - M4) +
                  ss[2] * __expf(sm[2] - M4) + ss[3] * __expf(sm[3] - M4);
  const float c = M4 + __logf(S);
  float4* p4 = (float4*)(X + (size_t)row * Vv);
  for (int j = tid; j < Vv / 4; j += 256) {
    float4 v = p4[j];
    v.x -= c; v.y -= c; v.z -= c; v.w -= c;
    p4[j] = v;
  }
}

// ---------------- final log-softmax (bf16 logits path): read bf16, write f32 d_out ----------------
__global__ __launch_bounds__(256) void lsm_final2_k(float* __restrict__ X,
                                                    const __hip_bfloat16* __restrict__ L,
                                                    const float2* __restrict__ P) {
  const int row = blockIdx.x;
  const int tid = threadIdx.x;
  float m = -3.4e38f, s = 0.f;
  for (int j = tid; j < 500; j += 256) {
    float2 p = P[(size_t)row * 500 + j];
    if (p.x > m) { s = s * __expf(m - p.x) + p.y; m = p.x; }
    else         { s += p.y * __expf(p.x - m); }
  }
  #pragma unroll
  for (int off2 = 32; off2 > 0; off2 >>= 1) {
    float mo = __shfl_down(m, off2);
    float so = __shfl_down(s, off2);
    float M = fmaxf(m, mo);
    s = s * __expf(m - M) + so * __expf(mo - M);
    m = M;
  }
  __shared__ float sm[4], ss[4];
  if ((tid & 63) == 0) { sm[tid >> 6] = m; ss[tid >> 6] = s; }
  __syncthreads();
  const float M4 = fmaxf(fmaxf(sm[0], sm[1]), fmaxf(sm[2], sm[3]));
  const float S = ss[0] * __expf(sm[0] - M4) + ss[1] * __expf(sm[1] - M4) +
                  ss[2] * __expf(sm[2] - M4) + ss[3] * __expf(sm[3] - M4);
  const float c = M4 + __logf(S);
  const short8* p8 = (const short8*)(L + (size_t)row * Vv);
  float4* o4 = (float4*)(X + (size_t)row * Vv);
  for (int j = tid; j < Vv / 8; j += 256) {
    short8 sv = p8[j];
    float4 a, b;
    a.x = __uint_as_float(((unsigned)(unsigned short)sv[0]) << 16) - c;
    a.y = __uint_as_float(((unsigned)(unsigned short)sv[1]) << 16) - c;
    a.z = __uint_as_float(((unsigned)(unsigned short)sv[2]) << 16) - c;
    a.w = __uint_as_float(((unsigned)(unsigned short)sv[3]) << 16) - c;
    b.x = __uint_as_float(((unsigned)(unsigned short)sv[4]) << 16) - c;
    b.y = __uint_as_float(((unsigned)(unsigned short)sv[5]) << 16) - c;
    b.z = __uint_as_float(((unsigned)(unsigned short)sv[6]) << 16) - c;
    b.w = __uint_as_float(((unsigned)(unsigned short)sv[7]) << 16) - c;
    o4[(j << 1)] = a;
    o4[(j << 1) + 1] = b;
  }
}

}  // namespace

extern "C" void kernel_launch(void* const* d_in, const int* in_sizes, int n_in,
                              void* d_out, int out_size, void* d_ws, size_t ws_size,
                              hipStream_t stream) {
  (void)in_sizes; (void)n_in; (void)out_size;
  const int*   in_seq  = (const int*)d_in[0];
  const int*   tgt_seq = (const int*)d_in[1];
  const float* enc_emb = (const float*)d_in[2];
  const float* enc_Wih = (const float*)d_in[3];
  const float* enc_Whh = (const float*)d_in[4];
  const float* enc_bih = (const float*)d_in[5];
  const float* enc_bhh = (const float*)d_in[6];
  const float* dec_emb = (const float*)d_in[7];
  const float* dec_Wih = (const float*)d_in[8];
  const float* dec_Whh = (const float*)d_in[9];
  const float* dec_bih = (const float*)d_in[10];
  const float* dec_bhh = (const float*)d_in[11];
  const float* out_W   = (const float*)d_in[12];
  const float* out_b   = (const float*)d_in[13];
  float* out = (float*)d_out;

  char* ws = (char*)d_ws;
  size_t off = 0;
  auto alloc = [&](size_t bytes) -> void* {
    void* p = (void*)(ws + off);
    off += (bytes + 255) & ~(size_t)255;
    return p;
  };
  uint2* whhB_e            = (uint2*)alloc((size_t)512 * 512 * 8);   // 2MB packed bf16
  uint2* whhB_d            = (uint2*)alloc((size_t)512 * 512 * 8);
  __hip_bfloat16* encWih_bf = (__hip_bfloat16*)alloc((size_t)1536 * 512 * 2);
  __hip_bfloat16* decWih_bf = (__hip_bfloat16*)alloc((size_t)1536 * 1024 * 2);
  __hip_bfloat16* outW_bf   = (__hip_bfloat16*)alloc((size_t)32000 * 512 * 2);
  __hip_bfloat16* encX_bf   = (__hip_bfloat16*)alloc((size_t)2048 * 512 * 2);
  __hip_bfloat16* decX_bf   = (__hip_bfloat16*)alloc((size_t)2048 * 512 * 2);
  float* enc_xp            = (float*)alloc((size_t)2048 * 1536 * 4);
  float* dec_xp            = (float*)alloc((size_t)2048 * 1536 * 4);
  float* tp                = (float*)alloc((size_t)128 * 1536 * 4);
  __hip_bfloat16* th_bf     = (__hip_bfloat16*)alloc((size_t)128 * 512 * 2);
  ull* hTag                = (ull*)alloc((size_t)2 * 32 * 512 * 8);  // 256KB tagged h
  __hip_bfloat16* decOut_bf = (__hip_bfloat16*)alloc((size_t)2048 * 512 * 2);
  float2* partials         = (float2*)alloc((size_t)2048 * 500 * 8); // 8.2MB softmax stats
  __hip_bfloat16* logitsBf  = (__hip_bfloat16*)alloc((size_t)2048 * Vv * 2);  // 131MB (optional)
  const bool bfLogits = (off <= ws_size);

  // --- weight preprocessing ---
  cvt_bf16_k<<<768, 256, 0, stream>>>(enc_Wih, encWih_bf, 1536 * 512 / 4);
  cvt_bf16_k<<<1536, 256, 0, stream>>>(dec_Wih, decWih_bf, 1536 * 1024 / 4);
  cvt_bf16_k<<<16000, 256, 0, stream>>>(out_W, outW_bf, 32000 * 512 / 4);
  pack_whh_bf_k<<<dim3(8, 16), 256, 0, stream>>>(enc_Whh, whhB_e);
  pack_whh_bf_k<<<dim3(8, 16), 256, 0, stream>>>(dec_Whh, whhB_d);

  // --- embeddings ---
  embed_k<<<2048, 128, 0, stream>>>(in_seq, enc_emb, encX_bf, 0);
  embed_k<<<2048, 128, 0, stream>>>(tgt_seq, dec_emb, decX_bf, 1);

  // --- encoder xp = enc_x @ Wih^T + bih : [2048,1536] ---
  gemm_bf16_k<<<192, 256, 0, stream>>>(encX_bf, encWih_bf, enc_xp, nullptr,
                                       512, 512, G3, 512, enc_bih, nullptr, nullptr, 16);

  // --- encoder GRU: persistent, 1 launch (FULL hTag zero: 65536 u32 -> both parities;
  //     round-9 audit found the old 128-block zero covered only half = stale-tag race) ---
  zero_k<<<256, 256, 0, stream>>>((unsigned*)hTag, 2 * 32 * 512 * 2);
  gru_seq7_k<<<dim3(16, 8), 512, 0, stream>>>(enc_xp, whhB_e, enc_bhh, hTag, nullptr);
  // h(64) tag 64 lives in buffer 0 (even parity)

  // --- tp = relu(thought) @ dec_Wih[:,512:]^T + dec_bih : [128(pad),1536] ---
  thought_prep2_k<<<128, 128, 0, stream>>>(hTag, th_bf);
  gemm_bf16_k<<<12, 256, 0, stream>>>(th_bf, decWih_bf + 512, tp, nullptr,
                                      512, 1024, G3, 512, dec_bih, nullptr, nullptr, 1);

  // --- decoder xp = relu(dec_x) @ dec_Wih[:,:512]^T + tp[b] : [2048,1536] ---
  gemm_bf16_k<<<192, 256, 0, stream>>>(decX_bf, decWih_bf, dec_xp, nullptr,
                                       512, 1024, G3, 512, nullptr, tp, nullptr, 16);

  // --- decoder GRU: persistent, 1 launch (FULL re-zero) ---
  zero_k<<<256, 256, 0, stream>>>((unsigned*)hTag, 2 * 32 * 512 * 2);
  gru_seq7_k<<<dim3(16, 8), 512, 0, stream>>>(dec_xp, whhB_d, dec_bhh, hTag, decOut_bf);

  if (bfLogits) {
    // --- logits (bf16) + fused softmax stats; final reads bf16, writes f32 d_out ---
    gemm_bf16_k<<<4000, 256, 0, stream>>>(decOut_bf, outW_bf, nullptr, logitsBf,
                                          512, 512, Vv, 512, out_b, nullptr, partials, 16);
    lsm_final2_k<<<2048, 256, 0, stream>>>(out, logitsBf, partials);
  } else {
    // --- fallback: f32 logits in d_out + in-place subtract ---
    gemm_bf16_k<<<4000, 256, 0, stream>>>(decOut_bf, outW_bf, out, nullptr,
                                          512, 512, Vv, 512, out_b, nullptr, partials, 16);
    lsm_final_k<<<2048, 256, 0, stream>>>(out, partials);
  }
}

// Round 11
// 953.770 us; speedup vs baseline: 1.3568x; 1.0438x over previous
//
#include <hip/hip_runtime.h>
#include <hip/hip_bf16.h>
#include <cstdint>
#include <cstddef>

namespace {

constexpr int Hh = 512;
constexpr int G3 = 1536;   // 3*H
constexpr int Bb = 32;
constexpr int Tt = 64;
constexpr int Vv = 32000;

typedef __attribute__((ext_vector_type(8))) short short8;
typedef __attribute__((ext_vector_type(4))) float f32x4;
typedef unsigned long long ull;

__device__ __forceinline__ unsigned bf16bits(float f) {
  union { __hip_bfloat16 h; unsigned short u; } c;
  c.h = __float2bfloat16(f);
  return (unsigned)c.u;
}

// async global->LDS, 16B per lane; LDS dest = wave-uniform base + lane*16
__device__ __forceinline__ void gl_lds16(const void* g, void* l) {
  __builtin_amdgcn_global_load_lds(
      (const __attribute__((address_space(1))) unsigned int*)g,
      (__attribute__((address_space(3))) unsigned int*)l, 16, 0, 0);
}

// ---------------- f32 -> bf16 convert (vectorized) ----------------
__global__ void cvt_bf16_k(const float* __restrict__ src, __hip_bfloat16* __restrict__ dst, int n4) {
  int i = blockIdx.x * blockDim.x + threadIdx.x;
  if (i >= n4) return;
  float4 v = ((const float4*)src)[i];
  union { __hip_bfloat16 h[4]; uint2 u; } o;
  o.h[0] = __float2bfloat16(v.x);
  o.h[1] = __float2bfloat16(v.y);
  o.h[2] = __float2bfloat16(v.z);
  o.h[3] = __float2bfloat16(v.w);
  ((uint2*)dst)[i] = o.u;
}

// ---------------- pack Whh[1536][512] -> P[k][i] = {bf16 r, bf16 z | bf16 n, 0} uint2, 2MB ----------------
__global__ void pack_whh_bf_k(const float* __restrict__ Whh, uint2* __restrict__ P) {
  __shared__ float tw[3][32][65];
  const int k0 = blockIdx.x * 64, i0 = blockIdx.y * 32;
  const int t = threadIdx.x;               // 256
  const int kk = t & 63, r4 = t >> 6;
  for (int ri = r4; ri < 96; ri += 4) {
    const int g = ri >> 5, ii = ri & 31;
    tw[g][ii][kk] = Whh[(size_t)(g * 512 + i0 + ii) * 512 + k0 + kk];
  }
  __syncthreads();
  const int ii = t & 31, kq = t >> 5;
  for (int k2 = kq; k2 < 64; k2 += 8) {
    unsigned rb = bf16bits(tw[0][ii][k2]);
    unsigned zb = bf16bits(tw[1][ii][k2]);
    unsigned nb = bf16bits(tw[2][ii][k2]);
    P[(size_t)(k0 + k2) * 512 + i0 + ii] = make_uint2((zb << 16) | rb, nb);
  }
}

// ---------------- embedding gather (optionally relu) -> bf16 [2048][512] ----------------
__global__ void embed_k(const int* __restrict__ idx, const float* __restrict__ emb,
                        __hip_bfloat16* __restrict__ outp, int do_relu) {
  int row = blockIdx.x;            // 0..2047 (= b*64+t)
  int r = idx[row];
  float4 v = ((const float4*)(emb + (size_t)r * Hh))[threadIdx.x];  // 128 thr * 4
  if (do_relu) {
    v.x = fmaxf(v.x, 0.f); v.y = fmaxf(v.y, 0.f);
    v.z = fmaxf(v.z, 0.f); v.w = fmaxf(v.w, 0.f);
  }
  union { __hip_bfloat16 h[4]; uint2 u; } o;
  o.h[0] = __float2bfloat16(v.x);
  o.h[1] = __float2bfloat16(v.y);
  o.h[2] = __float2bfloat16(v.z);
  o.h[3] = __float2bfloat16(v.w);
  ((uint2*)(outp + (size_t)row * Hh))[threadIdx.x] = o.u;
}

// ---------------- zero u32 ----------------
__global__ void zero_k(unsigned* __restrict__ p, int n) {
  int i = blockIdx.x * blockDim.x + threadIdx.x;
  if (i < n) p[i] = 0u;
}

// ---------------- relu(thought)->bf16 from tagged-h buffer, padded to 128 rows ----------------
__global__ void thought_prep2_k(const ull* __restrict__ th, __hip_bfloat16* __restrict__ outp) {
  int row = blockIdx.x;  // 0..127 ; 128 threads, 4 elems each
  const int c = threadIdx.x << 2;
  float4 v = {0.f, 0.f, 0.f, 0.f};
  if (row < Bb) {
    const ull* p = th + (size_t)row * Hh + c;
    v.x = __uint_as_float((unsigned)p[0]);
    v.y = __uint_as_float((unsigned)p[1]);
    v.z = __uint_as_float((unsigned)p[2]);
    v.w = __uint_as_float((unsigned)p[3]);
  }
  v.x = fmaxf(v.x, 0.f); v.y = fmaxf(v.y, 0.f);
  v.z = fmaxf(v.z, 0.f); v.w = fmaxf(v.w, 0.f);
  union { __hip_bfloat16 h[4]; uint2 u; } o;
  o.h[0] = __float2bfloat16(v.x);
  o.h[1] = __float2bfloat16(v.y);
  o.h[2] = __float2bfloat16(v.z);
  o.h[3] = __float2bfloat16(v.w);
  ((uint2*)(outp + (size_t)row * Hh))[threadIdx.x] = o.u;
}

// ---------------- bf16 MFMA GEMM (standalone): C = A*B^T (+bias1) ; partials mode -> bf16 C + stats ----------------
__global__ __launch_bounds__(256) void gemm_bf16_k(
    const __hip_bfloat16* __restrict__ A,
    const __hip_bfloat16* __restrict__ B,
    float* __restrict__ C,
    __hip_bfloat16* __restrict__ Cbf,
    int lda, int ldb, int ldc, int K,
    const float* __restrict__ bias1,
    float2* __restrict__ partials,
    int ntm) {
  __shared__ __align__(16) char smem[32768];
  auto sA = (__hip_bfloat16(*)[64])smem;            // [128][64]
  auto sB = (__hip_bfloat16(*)[64])(smem + 16384);  // [128][64]

  // bijective XCD-chunked swizzle
  const unsigned nwg = gridDim.x, gid = blockIdx.x;
  const unsigned q = nwg >> 3, r8 = nwg & 7, xc = gid & 7, jj = gid >> 3;
  const unsigned wg = (xc < r8 ? xc * (q + 1) : r8 * (q + 1) + (xc - r8) * q) + jj;
  const int m0 = (int)(wg % (unsigned)ntm) << 7;
  const int n0 = (int)(wg / (unsigned)ntm) << 7;

  const int tid = threadIdx.x;
  const int l = tid & 63, w = tid >> 6;
  const int wm = (w & 1) << 6, wn = (w >> 1) << 6;
  const int lr = l & 15;
  const int lk = (l >> 4) << 3;
  const int lrow = (w << 3) + (l >> 3);
  const int lcol = (l & 7) << 3;

  f32x4 acc[4][4];
  #pragma unroll
  for (int i = 0; i < 4; ++i)
    #pragma unroll
    for (int j = 0; j < 4; ++j) acc[i][j] = {0.f, 0.f, 0.f, 0.f};

  for (int k0 = 0; k0 < K; k0 += 64) {
    #pragma unroll
    for (int rr = 0; rr < 4; ++rr) {
      gl_lds16(A + (size_t)(m0 + (rr << 5) + lrow) * lda + k0 + lcol, &sA[(rr << 5) + (w << 3)][0]);
      gl_lds16(B + (size_t)(n0 + (rr << 5) + lrow) * ldb + k0 + lcol, &sB[(rr << 5) + (w << 3)][0]);
    }
    __syncthreads();
    #pragma unroll
    for (int kk = 0; kk < 64; kk += 32) {
      short8 aF[4], bF[4];
      #pragma unroll
      for (int ms = 0; ms < 4; ++ms) aF[ms] = *(const short8*)(&sA[wm + (ms << 4) + lr][kk + lk]);
      #pragma unroll
      for (int ns = 0; ns < 4; ++ns) bF[ns] = *(const short8*)(&sB[wn + (ns << 4) + lr][kk + lk]);
      #pragma unroll
      for (int ms = 0; ms < 4; ++ms)
        #pragma unroll
        for (int ns = 0; ns < 4; ++ns)
          acc[ms][ns] = __builtin_amdgcn_mfma_f32_16x16x32_bf16(aF[ms], bF[ns], acc[ms][ns], 0, 0, 0);
    }
    __syncthreads();
  }

  float* sg = (float*)smem + w * 1088;
  const int r2w = l >> 4;
  const int cw = l & 15;
  const int rbase = r2w << 2;
  #pragma unroll
  for (int ms = 0; ms < 4; ++ms) {
    #pragma unroll
    for (int ns = 0; ns < 4; ++ns)
      #pragma unroll
      for (int r = 0; r < 4; ++r) sg[(rbase + r) * 68 + (ns << 4) + lr] = acc[ms][ns][r];
    #pragma unroll
    for (int qq = 0; qq < 4; ++qq) {
      const int srow2 = (qq << 2) + r2w;
      float4 v = *(const float4*)&sg[srow2 * 68 + (cw << 2)];
      const int row = m0 + wm + (ms << 4) + srow2;
      const int col = n0 + wn + (cw << 2);
      if (bias1) {
        float4 b1 = *(const float4*)&bias1[col];
        v.x += b1.x; v.y += b1.y; v.z += b1.z; v.w += b1.w;
      }
      if (partials) {
        float m4 = fmaxf(fmaxf(v.x, v.y), fmaxf(v.z, v.w));
        #pragma unroll
        for (int hop = 1; hop < 16; hop <<= 1) m4 = fmaxf(m4, __shfl_xor(m4, hop));
        float e = __expf(v.x - m4) + __expf(v.y - m4) + __expf(v.z - m4) + __expf(v.w - m4);
        #pragma unroll
        for (int hop = 1; hop < 16; hop <<= 1) e += __shfl_xor(e, hop);
        if (cw == 0) partials[(size_t)row * 500 + ((n0 >> 6) + (wn >> 6))] = make_float2(m4, e);
        union { __hip_bfloat16 h[4]; uint2 u; } o;
        o.h[0] = __float2bfloat16(v.x);
        o.h[1] = __float2bfloat16(v.y);
        o.h[2] = __float2bfloat16(v.z);
        o.h[3] = __float2bfloat16(v.w);
        *(uint2*)&Cbf[(size_t)row * ldc + col] = o.u;
      } else {
        *(float4*)&C[(size_t)row * ldc + col] = v;
      }
    }
  }
}

// ---------------- GRU v5 core (PROVEN best: 296us/launch, conflict-free, 3 barriers) ----------------
// Called with 512 threads. tps: optional per-batch bias [128][1536] added to xp (decoder thought term).
// Sync: tagged-value h exchange via relaxed agent atomics (round-5/8 validated protocol).
__device__ __forceinline__ void gru_core(
    const int slice, const int bg,
    const float* __restrict__ xp, const uint2* __restrict__ whhB,
    const float* __restrict__ bhh, const float* __restrict__ tps,
    ull* __restrict__ hTag, __hip_bfloat16* __restrict__ dec_out,
    char* smem) {
  float* sH = (float*)smem;                 // 2048 f32 (8KB)
  float* sRed = (float*)(smem + 8192);      // 512*13 f32 (26.6KB)
  const int tid = threadIdx.x;
  const int i0 = slice << 5;
  const int il = tid & 31, kc = tid >> 5;   // 32 i x 16 k-chunks(32k each)
  const int kb0 = kc << 5;

  // step-invariant weights -> 96 VGPRs
  float wrF[32], wzF[32], wnF[32];
  {
    const uint2* wp = whhB + i0 + il;
    #pragma unroll
    for (int k4 = 0; k4 < 8; ++k4) {
      #pragma unroll
      for (int j = 0; j < 4; ++j) {
        const int idx = (k4 << 2) + j;
        uint2 wv = wp[(size_t)(kb0 + idx) << 9];
        wrF[idx] = __uint_as_float(wv.x << 16);
        wzF[idx] = __uint_as_float(wv.x & 0xffff0000u);
        wnF[idx] = __uint_as_float(wv.y << 16);
      }
    }
  }

  #pragma unroll 1
  for (int t = 0; t < Tt; ++t) {
    // poll + load h(t) from buffer (t parity); tag word = {step<<32 | f32}
    {
      const ull* hb = hTag + ((size_t)(t & 1) << 14) + ((size_t)bg << 11);
      #pragma unroll
      for (int j = 0; j < 4; ++j) {
        const ull* p = hb + (j << 9) + tid;
        ull v = __hip_atomic_load(p, __ATOMIC_RELAXED, __HIP_MEMORY_SCOPE_AGENT);
        while ((unsigned)(v >> 32) != (unsigned)t) {
          __builtin_amdgcn_s_sleep(1);
          v = __hip_atomic_load(p, __ATOMIC_RELAXED, __HIP_MEMORY_SCOPE_AGENT);
        }
        sH[(j << 9) + tid] = __uint_as_float((unsigned)v);
      }
    }
    __syncthreads();   // B0

    float a[12];
    #pragma unroll
    for (int v = 0; v < 12; ++v) a[v] = 0.f;
    #pragma unroll
    for (int k4 = 0; k4 < 8; ++k4) {
      const int kb = kb0 + (k4 << 2);
      float4 hv0 = *(const float4*)&sH[kb];
      float4 hv1 = *(const float4*)&sH[512 + kb];
      float4 hv2 = *(const float4*)&sH[1024 + kb];
      float4 hv3 = *(const float4*)&sH[1536 + kb];
      const float* h0p = (const float*)&hv0;
      const float* h1p = (const float*)&hv1;
      const float* h2p = (const float*)&hv2;
      const float* h3p = (const float*)&hv3;
      #pragma unroll
      for (int j = 0; j < 4; ++j) {
        const int idx = (k4 << 2) + j;
        const float wr = wrF[idx], wz = wzF[idx], wn = wnF[idx];
        a[0]  = fmaf(wr, h0p[j], a[0]);  a[1]  = fmaf(wz, h0p[j], a[1]);  a[2]  = fmaf(wn, h0p[j], a[2]);
        a[3]  = fmaf(wr, h1p[j], a[3]);  a[4]  = fmaf(wz, h1p[j], a[4]);  a[5]  = fmaf(wn, h1p[j], a[5]);
        a[6]  = fmaf(wr, h2p[j], a[6]);  a[7]  = fmaf(wz, h2p[j], a[7]);  a[8]  = fmaf(wn, h2p[j], a[8]);
        a[9]  = fmaf(wr, h3p[j], a[9]);  a[10] = fmaf(wz, h3p[j], a[10]); a[11] = fmaf(wn, h3p[j], a[11]);
      }
    }
    {
      float* red = &sRed[tid * 13];
      #pragma unroll
      for (int v = 0; v < 12; ++v) red[v] = a[v];
    }
    __syncthreads();   // B1

    if (tid < 128) {
      const int b = tid >> 5, i2 = tid & 31;
      float s0 = 0.f, s1 = 0.f, s2 = 0.f;
      #pragma unroll
      for (int kc2 = 0; kc2 < 16; ++kc2) {
        const float* rp = &sRed[(kc2 * 32 + i2) * 13 + b * 3];
        s0 += rp[0]; s1 += rp[1]; s2 += rp[2];
      }
      const int gi = i0 + i2;
      const int bb = (bg << 2) + b;
      const int m = bb * Tt + t;
      const float hr = s0 + bhh[gi];
      const float hz = s1 + bhh[512 + gi];
      const float hn = s2 + bhh[1024 + gi];
      float xr = xp[(size_t)m * G3 + gi];
      float xz = xp[(size_t)m * G3 + 512 + gi];
      float xn = xp[(size_t)m * G3 + 1024 + gi];
      if (tps) {
        xr += tps[(size_t)bb * G3 + gi];
        xz += tps[(size_t)bb * G3 + 512 + gi];
        xn += tps[(size_t)bb * G3 + 1024 + gi];
      }
      const float rg = 1.f / (1.f + __expf(-(xr + hr)));
      const float zg = 1.f / (1.f + __expf(-(xz + hz)));
      const float ng = tanhf(xn + rg * hn);
      const float hnew = (1.f - zg) * ng + zg * sH[(b << 9) + gi];
      ull* dst = hTag + ((size_t)((t + 1) & 1) << 14) + ((size_t)bb << 9) + gi;
      __hip_atomic_store(dst, ((ull)(unsigned)(t + 1) << 32) | (ull)__float_as_uint(hnew),
                         __ATOMIC_RELAXED, __HIP_MEMORY_SCOPE_AGENT);
      if (dec_out) dec_out[((size_t)m << 9) + gi] = __float2bfloat16(hnew);
    }
    __syncthreads();   // B2: protect sH/sRed
  }
}

// ---------------- 128x128 tile GEMM core for a 256-thread half-block (f32 out, no bias) ----------------
__device__ __forceinline__ void gemm_tile_core(
    const int tid, const int m0, const int n0,
    const __hip_bfloat16* __restrict__ A, const __hip_bfloat16* __restrict__ B,
    float* __restrict__ C, int lda, int ldb, int ldc, int K, char* smem) {
  auto sA = (__hip_bfloat16(*)[64])smem;            // [128][64]
  auto sB = (__hip_bfloat16(*)[64])(smem + 16384);  // [128][64]
  const int l = tid & 63, w = tid >> 6;
  const int wm = (w & 1) << 6, wn = (w >> 1) << 6;
  const int lr = l & 15;
  const int lk = (l >> 4) << 3;
  const int lrow = (w << 3) + (l >> 3);
  const int lcol = (l & 7) << 3;

  f32x4 acc[4][4];
  #pragma unroll
  for (int i = 0; i < 4; ++i)
    #pragma unroll
    for (int j = 0; j < 4; ++j) acc[i][j] = {0.f, 0.f, 0.f, 0.f};

  for (int k0 = 0; k0 < K; k0 += 64) {
    #pragma unroll
    for (int rr = 0; rr < 4; ++rr) {
      gl_lds16(A + (size_t)(m0 + (rr << 5) + lrow) * lda + k0 + lcol, &sA[(rr << 5) + (w << 3)][0]);
      gl_lds16(B + (size_t)(n0 + (rr << 5) + lrow) * ldb + k0 + lcol, &sB[(rr << 5) + (w << 3)][0]);
    }
    __syncthreads();
    #pragma unroll
    for (int kk = 0; kk < 64; kk += 32) {
      short8 aF[4], bF[4];
      #pragma unroll
      for (int ms = 0; ms < 4; ++ms) aF[ms] = *(const short8*)(&sA[wm + (ms << 4) + lr][kk + lk]);
      #pragma unroll
      for (int ns = 0; ns < 4; ++ns) bF[ns] = *(const short8*)(&sB[wn + (ns << 4) + lr][kk + lk]);
      #pragma unroll
      for (int ms = 0; ms < 4; ++ms)
        #pragma unroll
        for (int ns = 0; ns < 4; ++ns)
          acc[ms][ns] = __builtin_amdgcn_mfma_f32_16x16x32_bf16(aF[ms], bF[ns], acc[ms][ns], 0, 0, 0);
    }
    __syncthreads();
  }

  float* sg = (float*)smem + w * 1088;
  const int r2w = l >> 4;
  const int cw = l & 15;
  const int rbase = r2w << 2;
  #pragma unroll
  for (int ms = 0; ms < 4; ++ms) {
    #pragma unroll
    for (int ns = 0; ns < 4; ++ns)
      #pragma unroll
      for (int r = 0; r < 4; ++r) sg[(rbase + r) * 68 + (ns << 4) + lr] = acc[ms][ns][r];
    #pragma unroll
    for (int qq = 0; qq < 4; ++qq) {
      const int srow2 = (qq << 2) + r2w;
      float4 v = *(const float4*)&sg[srow2 * 68 + (cw << 2)];
      *(float4*)&C[(size_t)(m0 + wm + (ms << 4) + srow2) * ldc + n0 + wn + (cw << 2)] = v;
    }
  }
}

// ---------------- FUSED: encoder GRU (blocks 0-127) || dec_xp partial GEMM (128-223) || outW cvt (224-239) ----------------
// All three parts are mutually independent (dec_xp GEMM here EXCLUDES the tp term; tp is
// added in the decoder GRU tail). GRU blocks run the unchanged v5 protocol.
__global__ __launch_bounds__(512, 1) void enc_fused_k(
    const float* __restrict__ enc_xp, const uint2* __restrict__ whhB_e,
    const float* __restrict__ enc_bhh, ull* __restrict__ hTag,
    const __hip_bfloat16* __restrict__ decX_bf, const __hip_bfloat16* __restrict__ decWih_bf,
    float* __restrict__ dec_xp,
    const float* __restrict__ out_W, __hip_bfloat16* __restrict__ outW_bf) {
  __shared__ __align__(16) char smem[65536];
  const int blk = blockIdx.x;
  if (blk < 128) {
    gru_core(blk & 15, blk >> 4, enc_xp, whhB_e, enc_bhh, nullptr, hTag, nullptr, smem);
  } else if (blk < 224) {
    const int half = threadIdx.x >> 8;                  // 0/1
    const int tile = ((blk - 128) << 1) + half;         // 0..191
    const int m0 = (tile & 15) << 7;                    // 16 m-tiles
    const int n0 = (tile >> 4) << 7;                    // 12 n-tiles
    gemm_tile_core(threadIdx.x & 255, m0, n0, decX_bf, decWih_bf, dec_xp,
                   512, 1024, G3, 512, smem + (half << 15));
  } else {
    const int n4 = Vv * Hh / 4;                         // 4,096,000
    for (int i = ((blk - 224) << 9) + threadIdx.x; i < n4; i += 16 * 512) {
      float4 v = ((const float4*)out_W)[i];
      union { __hip_bfloat16 h[4]; uint2 u; } o;
      o.h[0] = __float2bfloat16(v.x);
      o.h[1] = __float2bfloat16(v.y);
      o.h[2] = __float2bfloat16(v.z);
      o.h[3] = __float2bfloat16(v.w);
      ((uint2*)outW_bf)[i] = o.u;
    }
  }
}

// ---------------- decoder GRU: plain launch of the v5 core (with tp bias) ----------------
__global__ __launch_bounds__(512, 1) void gru_seq_k2(
    const float* __restrict__ xp, const uint2* __restrict__ whhB,
    const float* __restrict__ bhh, const float* __restrict__ tps,
    ull* __restrict__ hTag, __hip_bfloat16* __restrict__ dec_out) {
  __shared__ __align__(16) char smem[34816];
  gru_core(blockIdx.x & 15, blockIdx.x >> 4, xp, whhB, bhh, tps, hTag, dec_out, smem);
}

// ---------------- final log-softmax (f32 logits fallback): reduce partials, subtract in place ----------------
__global__ __launch_bounds__(256) void lsm_final_k(float* __restrict__ X,
                                                   const float2* __restrict__ P) {
  const int row = blockIdx.x;
  const int tid = threadIdx.x;
  float m = -3.4e38f, s = 0.f;
  for (int j = tid; j < 500; j += 256) {
    float2 p = P[(size_t)row * 500 + j];
    if (p.x > m) { s = s * __expf(m - p.x) + p.y; m = p.x; }
    else         { s += p.y * __expf(p.x - m); }
  }
  #pragma unroll
  for (int off2 = 32; off2 > 0; off2 >>= 1) {
    float mo = __shfl_down(m, off2);
    float so = __shfl_down(s, off2);
    float M = fmaxf(m, mo);
    s = s * __expf(m - M) + so * __expf(mo - M);
    m = M;
  }
  __shared__ float sm[4], ss[4];
  if ((tid & 63) == 0) { sm[tid >> 6] = m; ss[tid >> 6] = s; }
  __syncthreads();
  const float M4 = fmaxf(fmaxf(sm[0], sm[1]), fmaxf(sm[2], sm[3]));
  const float S = ss[0] * __expf(sm[0] - M4) + ss[1] * __expf(sm[1] - M4) +
                  ss[2] * __expf(sm[2] - M4) + ss[3] * __expf(sm[3] - M4);
  const float c = M4 + __logf(S);
  float4* p4 = (float4*)(X + (size_t)row * Vv);
  for (int j = tid; j < Vv / 4; j += 256) {
    float4 v = p4[j];
    v.x -= c; v.y -= c; v.z -= c; v.w -= c;
    p4[j] = v;
  }
}

// ---------------- final log-softmax (bf16 logits path): read bf16, write f32 d_out ----------------
__global__ __launch_bounds__(256) void lsm_final2_k(float* __restrict__ X,
                                                    const __hip_bfloat16* __restrict__ L,
                                                    const float2* __restrict__ P) {
  const int row = blockIdx.x;
  const int tid = threadIdx.x;
  float m = -3.4e38f, s = 0.f;
  for (int j = tid; j < 500; j += 256) {
    float2 p = P[(size_t)row * 500 + j];
    if (p.x > m) { s = s * __expf(m - p.x) + p.y; m = p.x; }
    else         { s += p.y * __expf(p.x - m); }
  }
  #pragma unroll
  for (int off2 = 32; off2 > 0; off2 >>= 1) {
    float mo = __shfl_down(m, off2);
    float so = __shfl_down(s, off2);
    float M = fmaxf(m, mo);
    s = s * __expf(m - M) + so * __expf(mo - M);
    m = M;
  }
  __shared__ float sm[4], ss[4];
  if ((tid & 63) == 0) { sm[tid >> 6] = m; ss[tid >> 6] = s; }
  __syncthreads();
  const float M4 = fmaxf(fmaxf(sm[0], sm[1]), fmaxf(sm[2], sm[3]));
  const float S = ss[0] * __expf(sm[0] - M4) + ss[1] * __expf(sm[1] - M4) +
                  ss[2] * __expf(sm[2] - M4) + ss[3] * __expf(sm[3] - M4);
  const float c = M4 + __logf(S);
  const short8* p8 = (const short8*)(L + (size_t)row * Vv);
  float4* o4 = (float4*)(X + (size_t)row * Vv);
  for (int j = tid; j < Vv / 8; j += 256) {
    short8 sv = p8[j];
    float4 a, b;
    a.x = __uint_as_float(((unsigned)(unsigned short)sv[0]) << 16) - c;
    a.y = __uint_as_float(((unsigned)(unsigned short)sv[1]) << 16) - c;
    a.z = __uint_as_float(((unsigned)(unsigned short)sv[2]) << 16) - c;
    a.w = __uint_as_float(((unsigned)(unsigned short)sv[3]) << 16) - c;
    b.x = __uint_as_float(((unsigned)(unsigned short)sv[4]) << 16) - c;
    b.y = __uint_as_float(((unsigned)(unsigned short)sv[5]) << 16) - c;
    b.z = __uint_as_float(((unsigned)(unsigned short)sv[6]) << 16) - c;
    b.w = __uint_as_float(((unsigned)(unsigned short)sv[7]) << 16) - c;
    o4[(j << 1)] = a;
    o4[(j << 1) + 1] = b;
  }
}

}  // namespace

extern "C" void kernel_launch(void* const* d_in, const int* in_sizes, int n_in,
                              void* d_out, int out_size, void* d_ws, size_t ws_size,
                              hipStream_t stream) {
  (void)in_sizes; (void)n_in; (void)out_size;
  const int*   in_seq  = (const int*)d_in[0];
  const int*   tgt_seq = (const int*)d_in[1];
  const float* enc_emb = (const float*)d_in[2];
  const float* enc_Wih = (const float*)d_in[3];
  const float* enc_Whh = (const float*)d_in[4];
  const float* enc_bih = (const float*)d_in[5];
  const float* enc_bhh = (const float*)d_in[6];
  const float* dec_emb = (const float*)d_in[7];
  const float* dec_Wih = (const float*)d_in[8];
  const float* dec_Whh = (const float*)d_in[9];
  const float* dec_bih = (const float*)d_in[10];
  const float* dec_bhh = (const float*)d_in[11];
  const float* out_W   = (const float*)d_in[12];
  const float* out_b   = (const float*)d_in[13];
  float* out = (float*)d_out;

  char* ws = (char*)d_ws;
  size_t off = 0;
  auto alloc = [&](size_t bytes) -> void* {
    void* p = (void*)(ws + off);
    off += (bytes + 255) & ~(size_t)255;
    return p;
  };
  uint2* whhB_e            = (uint2*)alloc((size_t)512 * 512 * 8);   // 2MB packed bf16
  uint2* whhB_d            = (uint2*)alloc((size_t)512 * 512 * 8);
  __hip_bfloat16* encWih_bf = (__hip_bfloat16*)alloc((size_t)1536 * 512 * 2);
  __hip_bfloat16* decWih_bf = (__hip_bfloat16*)alloc((size_t)1536 * 1024 * 2);
  __hip_bfloat16* outW_bf   = (__hip_bfloat16*)alloc((size_t)32000 * 512 * 2);
  __hip_bfloat16* encX_bf   = (__hip_bfloat16*)alloc((size_t)2048 * 512 * 2);
  __hip_bfloat16* decX_bf   = (__hip_bfloat16*)alloc((size_t)2048 * 512 * 2);
  float* enc_xp            = (float*)alloc((size_t)2048 * 1536 * 4);
  float* dec_xp            = (float*)alloc((size_t)2048 * 1536 * 4);
  float* tp                = (float*)alloc((size_t)128 * 1536 * 4);
  __hip_bfloat16* th_bf     = (__hip_bfloat16*)alloc((size_t)128 * 512 * 2);
  ull* hTag                = (ull*)alloc((size_t)2 * 32 * 512 * 8);  // 256KB tagged h
  __hip_bfloat16* decOut_bf = (__hip_bfloat16*)alloc((size_t)2048 * 512 * 2);
  float2* partials         = (float2*)alloc((size_t)2048 * 500 * 8); // 8.2MB softmax stats
  __hip_bfloat16* logitsBf  = (__hip_bfloat16*)alloc((size_t)2048 * Vv * 2);  // 131MB (optional)
  const bool bfLogits = (off <= ws_size);

  // --- weight preprocessing (Wih converts + Whh packs; outW cvt is fused later) ---
  cvt_bf16_k<<<768, 256, 0, stream>>>(enc_Wih, encWih_bf, 1536 * 512 / 4);
  cvt_bf16_k<<<1536, 256, 0, stream>>>(dec_Wih, decWih_bf, 1536 * 1024 / 4);
  pack_whh_bf_k<<<dim3(8, 16), 256, 0, stream>>>(enc_Whh, whhB_e);
  pack_whh_bf_k<<<dim3(8, 16), 256, 0, stream>>>(dec_Whh, whhB_d);

  // --- embeddings ---
  embed_k<<<2048, 128, 0, stream>>>(in_seq, enc_emb, encX_bf, 0);
  embed_k<<<2048, 128, 0, stream>>>(tgt_seq, dec_emb, decX_bf, 1);

  // --- encoder xp = enc_x @ Wih^T + bih : [2048,1536] ---
  gemm_bf16_k<<<192, 256, 0, stream>>>(encX_bf, encWih_bf, enc_xp, nullptr,
                                       512, 512, G3, 512, enc_bih, nullptr, 16);

  // --- FULL hTag zero (65536 u32, both parities — round-9 stale-tag fix) ---
  zero_k<<<256, 256, 0, stream>>>((unsigned*)hTag, 2 * 32 * 512 * 2);

  // --- FUSED: encoder GRU || dec_xp partial GEMM (no tp) || outW bf16 cvt ---
  enc_fused_k<<<240, 512, 0, stream>>>(enc_xp, whhB_e, enc_bhh, hTag,
                                       decX_bf, decWih_bf, dec_xp, out_W, outW_bf);
  // h(64) tag 64 lives in hTag buffer 0 (even parity)

  // --- tp = relu(thought) @ dec_Wih[:,512:]^T + dec_bih : [128(pad),1536] ---
  thought_prep2_k<<<128, 128, 0, stream>>>(hTag, th_bf);
  gemm_bf16_k<<<12, 256, 0, stream>>>(th_bf, decWih_bf + 512, tp, nullptr,
                                      512, 1024, G3, 512, dec_bih, nullptr, 1);

  // --- decoder GRU (v5 core + tp added in tail) ---
  zero_k<<<256, 256, 0, stream>>>((unsigned*)hTag, 2 * 32 * 512 * 2);
  gru_seq_k2<<<128, 512, 0, stream>>>(dec_xp, whhB_d, dec_bhh, tp, hTag, decOut_bf);

  if (bfLogits) {
    gemm_bf16_k<<<4000, 256, 0, stream>>>(decOut_bf, outW_bf, nullptr, logitsBf,
                                          512, 512, Vv, 512, out_b, partials, 16);
    lsm_final2_k<<<2048, 256, 0, stream>>>(out, logitsBf, partials);
  } else {
    gemm_bf16_k<<<4000, 256, 0, stream>>>(decOut_bf, outW_bf, out, nullptr,
                                          512, 512, Vv, 512, out_b, partials, 16);
    lsm_final_k<<<2048, 256, 0, stream>>>(out, partials);
  }
}

// Round 12
// 930.276 us; speedup vs baseline: 1.3911x; 1.0253x over previous
//
#include <hip/hip_runtime.h>
#include <hip/hip_bf16.h>
#include <cstdint>
#include <cstddef>

namespace {

constexpr int Hh = 512;
constexpr int G3 = 1536;   // 3*H
constexpr int Bb = 32;
constexpr int Tt = 64;
constexpr int Vv = 32000;

typedef __attribute__((ext_vector_type(8))) short short8;
typedef __attribute__((ext_vector_type(4))) float f32x4;
typedef unsigned long long ull;

__device__ __forceinline__ unsigned bf16bits(float f) {
  union { __hip_bfloat16 h; unsigned short u; } c;
  c.h = __float2bfloat16(f);
  return (unsigned)c.u;
}

// async global->LDS, 16B per lane; LDS dest = wave-uniform base + lane*16
__device__ __forceinline__ void gl_lds16(const void* g, void* l) {
  __builtin_amdgcn_global_load_lds(
      (const __attribute__((address_space(1))) unsigned int*)g,
      (__attribute__((address_space(3))) unsigned int*)l, 16, 0, 0);
}

// ---------------- f32 -> bf16 convert (vectorized) ----------------
__global__ void cvt_bf16_k(const float* __restrict__ src, __hip_bfloat16* __restrict__ dst, int n4) {
  int i = blockIdx.x * blockDim.x + threadIdx.x;
  if (i >= n4) return;
  float4 v = ((const float4*)src)[i];
  union { __hip_bfloat16 h[4]; uint2 u; } o;
  o.h[0] = __float2bfloat16(v.x);
  o.h[1] = __float2bfloat16(v.y);
  o.h[2] = __float2bfloat16(v.z);
  o.h[3] = __float2bfloat16(v.w);
  ((uint2*)dst)[i] = o.u;
}

// ---------------- pack Whh[1536][512] -> P[k][i] = {bf16 r, bf16 z | bf16 n, 0} uint2, 2MB ----------------
__global__ void pack_whh_bf_k(const float* __restrict__ Whh, uint2* __restrict__ P) {
  __shared__ float tw[3][32][65];
  const int k0 = blockIdx.x * 64, i0 = blockIdx.y * 32;
  const int t = threadIdx.x;               // 256
  const int kk = t & 63, r4 = t >> 6;
  for (int ri = r4; ri < 96; ri += 4) {
    const int g = ri >> 5, ii = ri & 31;
    tw[g][ii][kk] = Whh[(size_t)(g * 512 + i0 + ii) * 512 + k0 + kk];
  }
  __syncthreads();
  const int ii = t & 31, kq = t >> 5;
  for (int k2 = kq; k2 < 64; k2 += 8) {
    unsigned rb = bf16bits(tw[0][ii][k2]);
    unsigned zb = bf16bits(tw[1][ii][k2]);
    unsigned nb = bf16bits(tw[2][ii][k2]);
    P[(size_t)(k0 + k2) * 512 + i0 + ii] = make_uint2((zb << 16) | rb, nb);
  }
}

// ---------------- embedding gather (optionally relu) -> bf16 [2048][512] ----------------
__global__ void embed_k(const int* __restrict__ idx, const float* __restrict__ emb,
                        __hip_bfloat16* __restrict__ outp, int do_relu) {
  int row = blockIdx.x;            // 0..2047 (= b*64+t)
  int r = idx[row];
  float4 v = ((const float4*)(emb + (size_t)r * Hh))[threadIdx.x];  // 128 thr * 4
  if (do_relu) {
    v.x = fmaxf(v.x, 0.f); v.y = fmaxf(v.y, 0.f);
    v.z = fmaxf(v.z, 0.f); v.w = fmaxf(v.w, 0.f);
  }
  union { __hip_bfloat16 h[4]; uint2 u; } o;
  o.h[0] = __float2bfloat16(v.x);
  o.h[1] = __float2bfloat16(v.y);
  o.h[2] = __float2bfloat16(v.z);
  o.h[3] = __float2bfloat16(v.w);
  ((uint2*)(outp + (size_t)row * Hh))[threadIdx.x] = o.u;
}

// ---------------- zero u32 ----------------
__global__ void zero_k(unsigned* __restrict__ p, int n) {
  int i = blockIdx.x * blockDim.x + threadIdx.x;
  if (i < n) p[i] = 0u;
}

// ---------------- bf16 MFMA GEMM (standalone): C = A*B^T (+bias1) ; partials mode -> bf16 C + stats ----------------
__global__ __launch_bounds__(256) void gemm_bf16_k(
    const __hip_bfloat16* __restrict__ A,
    const __hip_bfloat16* __restrict__ B,
    float* __restrict__ C,
    __hip_bfloat16* __restrict__ Cbf,
    int lda, int ldb, int ldc, int K,
    const float* __restrict__ bias1,
    float2* __restrict__ partials,
    int ntm) {
  __shared__ __align__(16) char smem[32768];
  auto sA = (__hip_bfloat16(*)[64])smem;            // [128][64]
  auto sB = (__hip_bfloat16(*)[64])(smem + 16384);  // [128][64]

  // bijective XCD-chunked swizzle
  const unsigned nwg = gridDim.x, gid = blockIdx.x;
  const unsigned q = nwg >> 3, r8 = nwg & 7, xc = gid & 7, jj = gid >> 3;
  const unsigned wg = (xc < r8 ? xc * (q + 1) : r8 * (q + 1) + (xc - r8) * q) + jj;
  const int m0 = (int)(wg % (unsigned)ntm) << 7;
  const int n0 = (int)(wg / (unsigned)ntm) << 7;

  const int tid = threadIdx.x;
  const int l = tid & 63, w = tid >> 6;
  const int wm = (w & 1) << 6, wn = (w >> 1) << 6;
  const int lr = l & 15;
  const int lk = (l >> 4) << 3;
  const int lrow = (w << 3) + (l >> 3);
  const int lcol = (l & 7) << 3;

  f32x4 acc[4][4];
  #pragma unroll
  for (int i = 0; i < 4; ++i)
    #pragma unroll
    for (int j = 0; j < 4; ++j) acc[i][j] = {0.f, 0.f, 0.f, 0.f};

  for (int k0 = 0; k0 < K; k0 += 64) {
    #pragma unroll
    for (int rr = 0; rr < 4; ++rr) {
      gl_lds16(A + (size_t)(m0 + (rr << 5) + lrow) * lda + k0 + lcol, &sA[(rr << 5) + (w << 3)][0]);
      gl_lds16(B + (size_t)(n0 + (rr << 5) + lrow) * ldb + k0 + lcol, &sB[(rr << 5) + (w << 3)][0]);
    }
    __syncthreads();
    #pragma unroll
    for (int kk = 0; kk < 64; kk += 32) {
      short8 aF[4], bF[4];
      #pragma unroll
      for (int ms = 0; ms < 4; ++ms) aF[ms] = *(const short8*)(&sA[wm + (ms << 4) + lr][kk + lk]);
      #pragma unroll
      for (int ns = 0; ns < 4; ++ns) bF[ns] = *(const short8*)(&sB[wn + (ns << 4) + lr][kk + lk]);
      #pragma unroll
      for (int ms = 0; ms < 4; ++ms)
        #pragma unroll
        for (int ns = 0; ns < 4; ++ns)
          acc[ms][ns] = __builtin_amdgcn_mfma_f32_16x16x32_bf16(aF[ms], bF[ns], acc[ms][ns], 0, 0, 0);
    }
    __syncthreads();
  }

  float* sg = (float*)smem + w * 1088;
  const int r2w = l >> 4;
  const int cw = l & 15;
  const int rbase = r2w << 2;
  #pragma unroll
  for (int ms = 0; ms < 4; ++ms) {
    #pragma unroll
    for (int ns = 0; ns < 4; ++ns)
      #pragma unroll
      for (int r = 0; r < 4; ++r) sg[(rbase + r) * 68 + (ns << 4) + lr] = acc[ms][ns][r];
    #pragma unroll
    for (int qq = 0; qq < 4; ++qq) {
      const int srow2 = (qq << 2) + r2w;
      float4 v = *(const float4*)&sg[srow2 * 68 + (cw << 2)];
      const int row = m0 + wm + (ms << 4) + srow2;
      const int col = n0 + wn + (cw << 2);
      if (bias1) {
        float4 b1 = *(const float4*)&bias1[col];
        v.x += b1.x; v.y += b1.y; v.z += b1.z; v.w += b1.w;
      }
      if (partials) {
        float m4 = fmaxf(fmaxf(v.x, v.y), fmaxf(v.z, v.w));
        #pragma unroll
        for (int hop = 1; hop < 16; hop <<= 1) m4 = fmaxf(m4, __shfl_xor(m4, hop));
        float e = __expf(v.x - m4) + __expf(v.y - m4) + __expf(v.z - m4) + __expf(v.w - m4);
        #pragma unroll
        for (int hop = 1; hop < 16; hop <<= 1) e += __shfl_xor(e, hop);
        if (cw == 0) partials[(size_t)row * 500 + ((n0 >> 6) + (wn >> 6))] = make_float2(m4, e);
        union { __hip_bfloat16 h[4]; uint2 u; } o;
        o.h[0] = __float2bfloat16(v.x);
        o.h[1] = __float2bfloat16(v.y);
        o.h[2] = __float2bfloat16(v.z);
        o.h[3] = __float2bfloat16(v.w);
        *(uint2*)&Cbf[(size_t)row * ldc + col] = o.u;
      } else {
        *(float4*)&C[(size_t)row * ldc + col] = v;
      }
    }
  }
}

// ---------------- GRU core (v5 protocol, PROVEN 296us) + invariant hoisting ----------------
// Called with 512 threads, smem >= 34816B.
// New vs round-11: (a) bhh + tp hoisted to registers (tp was re-loaded 64x/step!);
// (b) thought-projection tp = relu(thought)@W2^T + dec_bih computed IN-PROLOGUE from the
//     encoder's hTag buffer (replaces 2 serial launches); (c) xp(t+1) prefetch in tail.
// Cross-block protocol (tagged-value h exchange, relaxed agent atomics) byte-identical to v5.
__device__ __forceinline__ void gru_core(
    const int slice, const int bg,
    const float* __restrict__ xp, const uint2* __restrict__ whhB,
    const float* __restrict__ bhh,
    ull* __restrict__ hTag, __hip_bfloat16* __restrict__ dec_out,
    char* smem,
    const ull* __restrict__ thoughtTag,   // null or encoder hTag buf0 (thought w/ tag 64)
    const float* __restrict__ decWih,     // f32 [1536][1024] (only if thoughtTag)
    const float* __restrict__ dec_bih) {  // f32 [1536]       (only if thoughtTag)
  float* sH = (float*)smem;                 // 2048 f32 (8KB)
  float* sRed = (float*)(smem + 8192);      // 512*13 f32 (26.6KB)
  const int tid = threadIdx.x;
  const int i0 = slice << 5;
  const int il = tid & 31, kc = tid >> 5;   // 32 i x 16 k-chunks(32k each)
  const int kb0 = kc << 5;

  // ---- step-invariant weights -> 96 VGPRs ----
  float wrF[32], wzF[32], wnF[32];
  {
    const uint2* wp = whhB + i0 + il;
    #pragma unroll
    for (int k4 = 0; k4 < 8; ++k4) {
      #pragma unroll
      for (int j = 0; j < 4; ++j) {
        const int idx = (k4 << 2) + j;
        uint2 wv = wp[(size_t)(kb0 + idx) << 9];
        wrF[idx] = __uint_as_float(wv.x << 16);
        wzF[idx] = __uint_as_float(wv.x & 0xffff0000u);
        wnF[idx] = __uint_as_float(wv.y << 16);
      }
    }
  }

  // ---- tail invariants: bhh, tp (thought projection), first-step xp ----
  float bh_r = 0.f, bh_z = 0.f, bh_n = 0.f;
  float tpr = 0.f, tpz = 0.f, tpn = 0.f;
  float xr = 0.f, xz = 0.f, xn = 0.f;
  int gi = 0, bb = 0;
  if (tid < 128) {
    const int b = tid >> 5, i2 = tid & 31;
    gi = i0 + i2;
    bb = (bg << 2) + b;
    bh_r = bhh[gi]; bh_z = bhh[512 + gi]; bh_n = bhh[1024 + gi];
  }
  if (thoughtTag) {
    // relu(thought) for this bg's 4 batches -> sH (value = low 32 bits of tag word)
    #pragma unroll
    for (int j = 0; j < 4; ++j) {
      ull v = __hip_atomic_load(thoughtTag + ((size_t)bg << 11) + (j << 9) + tid,
                                __ATOMIC_RELAXED, __HIP_MEMORY_SCOPE_AGENT);
      sH[(j << 9) + tid] = fmaxf(__uint_as_float((unsigned)v), 0.f);
    }
    __syncthreads();
    // 384 threads: one (batch b, gate-row) output each; dot over k=512 (f32)
    if (tid < 384) {
      const int b = tid / 96, j = tid % 96;
      const int g = j >> 5, i2 = j & 31;
      const int row = g * 512 + i0 + i2;
      const float4* w4 = (const float4*)(decWih + (size_t)row * 1024 + 512);
      const float* th = &sH[b << 9];
      float s = dec_bih[row];
      #pragma unroll 4
      for (int k = 0; k < 128; ++k) {
        float4 w = w4[k];
        float4 t4 = *(const float4*)&th[k << 2];
        s += w.x * t4.x + w.y * t4.y + w.z * t4.z + w.w * t4.w;
      }
      sRed[tid] = s;
    }
    __syncthreads();
    if (tid < 128) {
      const int b = tid >> 5, i2 = tid & 31;
      tpr = sRed[b * 96 + i2];
      tpz = sRed[b * 96 + 32 + i2];
      tpn = sRed[b * 96 + 64 + i2];
    }
    __syncthreads();
  }
  if (tid < 128) {
    const size_t m = (size_t)bb * Tt;  // t = 0
    xr = xp[m * G3 + gi] + tpr;
    xz = xp[m * G3 + 512 + gi] + tpz;
    xn = xp[m * G3 + 1024 + gi] + tpn;
  }

  #pragma unroll 1
  for (int t = 0; t < Tt; ++t) {
    // poll + load h(t) from buffer (t parity); tag word = {step<<32 | f32}
    {
      const ull* hb = hTag + ((size_t)(t & 1) << 14) + ((size_t)bg << 11);
      #pragma unroll
      for (int j = 0; j < 4; ++j) {
        const ull* p = hb + (j << 9) + tid;
        ull v = __hip_atomic_load(p, __ATOMIC_RELAXED, __HIP_MEMORY_SCOPE_AGENT);
        while ((unsigned)(v >> 32) != (unsigned)t) {
          __builtin_amdgcn_s_sleep(1);
          v = __hip_atomic_load(p, __ATOMIC_RELAXED, __HIP_MEMORY_SCOPE_AGENT);
        }
        sH[(j << 9) + tid] = __uint_as_float((unsigned)v);
      }
    }
    __syncthreads();   // B0

    float a[12];
    #pragma unroll
    for (int v = 0; v < 12; ++v) a[v] = 0.f;
    #pragma unroll
    for (int k4 = 0; k4 < 8; ++k4) {
      const int kb = kb0 + (k4 << 2);
      float4 hv0 = *(const float4*)&sH[kb];
      float4 hv1 = *(const float4*)&sH[512 + kb];
      float4 hv2 = *(const float4*)&sH[1024 + kb];
      float4 hv3 = *(const float4*)&sH[1536 + kb];
      const float* h0p = (const float*)&hv0;
      const float* h1p = (const float*)&hv1;
      const float* h2p = (const float*)&hv2;
      const float* h3p = (const float*)&hv3;
      #pragma unroll
      for (int j = 0; j < 4; ++j) {
        const int idx = (k4 << 2) + j;
        const float wr = wrF[idx], wz = wzF[idx], wn = wnF[idx];
        a[0]  = fmaf(wr, h0p[j], a[0]);  a[1]  = fmaf(wz, h0p[j], a[1]);  a[2]  = fmaf(wn, h0p[j], a[2]);
        a[3]  = fmaf(wr, h1p[j], a[3]);  a[4]  = fmaf(wz, h1p[j], a[4]);  a[5]  = fmaf(wn, h1p[j], a[5]);
        a[6]  = fmaf(wr, h2p[j], a[6]);  a[7]  = fmaf(wz, h2p[j], a[7]);  a[8]  = fmaf(wn, h2p[j], a[8]);
        a[9]  = fmaf(wr, h3p[j], a[9]);  a[10] = fmaf(wz, h3p[j], a[10]); a[11] = fmaf(wn, h3p[j], a[11]);
      }
    }
    {
      float* red = &sRed[tid * 13];
      #pragma unroll
      for (int v = 0; v < 12; ++v) red[v] = a[v];
    }
    __syncthreads();   // B1

    if (tid < 128) {
      const int b = tid >> 5, i2 = tid & 31;
      float s0 = 0.f, s1 = 0.f, s2 = 0.f;
      #pragma unroll
      for (int kc2 = 0; kc2 < 16; ++kc2) {
        const float* rp = &sRed[(kc2 * 32 + i2) * 13 + b * 3];
        s0 += rp[0]; s1 += rp[1]; s2 += rp[2];
      }
      const float hr = s0 + bh_r;
      const float hz = s1 + bh_z;
      const float hn = s2 + bh_n;
      const float rg = 1.f / (1.f + __expf(-(xr + hr)));
      const float zg = 1.f / (1.f + __expf(-(xz + hz)));
      const float ng = tanhf(xn + rg * hn);
      const float hnew = (1.f - zg) * ng + zg * sH[(b << 9) + gi];
      ull* dst = hTag + ((size_t)((t + 1) & 1) << 14) + ((size_t)bb << 9) + gi;
      __hip_atomic_store(dst, ((ull)(unsigned)(t + 1) << 32) | (ull)__float_as_uint(hnew),
                         __ATOMIC_RELAXED, __HIP_MEMORY_SCOPE_AGENT);
      if (dec_out) dec_out[((size_t)(bb * Tt + t) << 9) + gi] = __float2bfloat16(hnew);
      if (t + 1 < Tt) {   // prefetch next step's xp (off critical path)
        const size_t m = (size_t)bb * Tt + (t + 1);
        xr = xp[m * G3 + gi] + tpr;
        xz = xp[m * G3 + 512 + gi] + tpz;
        xn = xp[m * G3 + 1024 + gi] + tpn;
      }
    }
    __syncthreads();   // B2: protect sH/sRed
  }
}

// ---------------- 128x128 tile GEMM core for a 256-thread half-block (f32 out, no bias) ----------------
__device__ __forceinline__ void gemm_tile_core(
    const int tid, const int m0, const int n0,
    const __hip_bfloat16* __restrict__ A, const __hip_bfloat16* __restrict__ B,
    float* __restrict__ C, int lda, int ldb, int ldc, int K, char* smem) {
  auto sA = (__hip_bfloat16(*)[64])smem;            // [128][64]
  auto sB = (__hip_bfloat16(*)[64])(smem + 16384);  // [128][64]
  const int l = tid & 63, w = tid >> 6;
  const int wm = (w & 1) << 6, wn = (w >> 1) << 6;
  const int lr = l & 15;
  const int lk = (l >> 4) << 3;
  const int lrow = (w << 3) + (l >> 3);
  const int lcol = (l & 7) << 3;

  f32x4 acc[4][4];
  #pragma unroll
  for (int i = 0; i < 4; ++i)
    #pragma unroll
    for (int j = 0; j < 4; ++j) acc[i][j] = {0.f, 0.f, 0.f, 0.f};

  for (int k0 = 0; k0 < K; k0 += 64) {
    #pragma unroll
    for (int rr = 0; rr < 4; ++rr) {
      gl_lds16(A + (size_t)(m0 + (rr << 5) + lrow) * lda + k0 + lcol, &sA[(rr << 5) + (w << 3)][0]);
      gl_lds16(B + (size_t)(n0 + (rr << 5) + lrow) * ldb + k0 + lcol, &sB[(rr << 5) + (w << 3)][0]);
    }
    __syncthreads();
    #pragma unroll
    for (int kk = 0; kk < 64; kk += 32) {
      short8 aF[4], bF[4];
      #pragma unroll
      for (int ms = 0; ms < 4; ++ms) aF[ms] = *(const short8*)(&sA[wm + (ms << 4) + lr][kk + lk]);
      #pragma unroll
      for (int ns = 0; ns < 4; ++ns) bF[ns] = *(const short8*)(&sB[wn + (ns << 4) + lr][kk + lk]);
      #pragma unroll
      for (int ms = 0; ms < 4; ++ms)
        #pragma unroll
        for (int ns = 0; ns < 4; ++ns)
          acc[ms][ns] = __builtin_amdgcn_mfma_f32_16x16x32_bf16(aF[ms], bF[ns], acc[ms][ns], 0, 0, 0);
    }
    __syncthreads();
  }

  float* sg = (float*)smem + w * 1088;
  const int r2w = l >> 4;
  const int cw = l & 15;
  const int rbase = r2w << 2;
  #pragma unroll
  for (int ms = 0; ms < 4; ++ms) {
    #pragma unroll
    for (int ns = 0; ns < 4; ++ns)
      #pragma unroll
      for (int r = 0; r < 4; ++r) sg[(rbase + r) * 68 + (ns << 4) + lr] = acc[ms][ns][r];
    #pragma unroll
    for (int qq = 0; qq < 4; ++qq) {
      const int srow2 = (qq << 2) + r2w;
      float4 v = *(const float4*)&sg[srow2 * 68 + (cw << 2)];
      *(float4*)&C[(size_t)(m0 + wm + (ms << 4) + srow2) * ldc + n0 + wn + (cw << 2)] = v;
    }
  }
}

// ---------------- FUSED: encoder GRU (blocks 0-127) || dec_xp partial GEMM (128-223) || outW cvt (224-239) ----------------
__global__ __launch_bounds__(512, 1) void enc_fused_k(
    const float* __restrict__ enc_xp, const uint2* __restrict__ whhB_e,
    const float* __restrict__ enc_bhh, ull* __restrict__ hTag_e,
    const __hip_bfloat16* __restrict__ decX_bf, const __hip_bfloat16* __restrict__ decWih_bf,
    float* __restrict__ dec_xp,
    const float* __restrict__ out_W, __hip_bfloat16* __restrict__ outW_bf) {
  __shared__ __align__(16) char smem[65536];
  const int blk = blockIdx.x;
  if (blk < 128) {
    gru_core(blk & 15, blk >> 4, enc_xp, whhB_e, enc_bhh, hTag_e, nullptr, smem,
             nullptr, nullptr, nullptr);
  } else if (blk < 224) {
    const int half = threadIdx.x >> 8;                  // 0/1
    const int tile = ((blk - 128) << 1) + half;         // 0..191
    const int m0 = (tile & 15) << 7;                    // 16 m-tiles
    const int n0 = (tile >> 4) << 7;                    // 12 n-tiles
    gemm_tile_core(threadIdx.x & 255, m0, n0, decX_bf, decWih_bf, dec_xp,
                   512, 1024, G3, 512, smem + (half << 15));
  } else {
    const int n4 = Vv * Hh / 4;                         // 4,096,000
    for (int i = ((blk - 224) << 9) + threadIdx.x; i < n4; i += 16 * 512) {
      float4 v = ((const float4*)out_W)[i];
      union { __hip_bfloat16 h[4]; uint2 u; } o;
      o.h[0] = __float2bfloat16(v.x);
      o.h[1] = __float2bfloat16(v.y);
      o.h[2] = __float2bfloat16(v.z);
      o.h[3] = __float2bfloat16(v.w);
      ((uint2*)outW_bf)[i] = o.u;
    }
  }
}

// ---------------- decoder GRU: v5 core + in-prologue thought projection ----------------
__global__ __launch_bounds__(512, 1) void gru_dec_k(
    const float* __restrict__ xp, const uint2* __restrict__ whhB,
    const float* __restrict__ bhh,
    const ull* __restrict__ thoughtTag,   // encoder hTag buf0 (thought, tag 64)
    const float* __restrict__ decWih, const float* __restrict__ dec_bih,
    ull* __restrict__ hTag, __hip_bfloat16* __restrict__ dec_out) {
  __shared__ __align__(16) char smem[34816];
  gru_core(blockIdx.x & 15, blockIdx.x >> 4, xp, whhB, bhh, hTag, dec_out, smem,
           thoughtTag, decWih, dec_bih);
}

// ---------------- final log-softmax (f32 logits fallback): reduce partials, subtract in place ----------------
__global__ __launch_bounds__(256) void lsm_final_k(float* __restrict__ X,
                                                   const float2* __restrict__ P) {
  const int row = blockIdx.x;
  const int tid = threadIdx.x;
  float m = -3.4e38f, s = 0.f;
  for (int j = tid; j < 500; j += 256) {
    float2 p = P[(size_t)row * 500 + j];
    if (p.x > m) { s = s * __expf(m - p.x) + p.y; m = p.x; }
    else         { s += p.y * __expf(p.x - m); }
  }
  #pragma unroll
  for (int off2 = 32; off2 > 0; off2 >>= 1) {
    float mo = __shfl_down(m, off2);
    float so = __shfl_down(s, off2);
    float M = fmaxf(m, mo);
    s = s * __expf(m - M) + so * __expf(mo - M);
    m = M;
  }
  __shared__ float sm[4], ss[4];
  if ((tid & 63) == 0) { sm[tid >> 6] = m; ss[tid >> 6] = s; }
  __syncthreads();
  const float M4 = fmaxf(fmaxf(sm[0], sm[1]), fmaxf(sm[2], sm[3]));
  const float S = ss[0] * __expf(sm[0] - M4) + ss[1] * __expf(sm[1] - M4) +
                  ss[2] * __expf(sm[2] - M4) + ss[3] * __expf(sm[3] - M4);
  const float c = M4 + __logf(S);
  float4* p4 = (float4*)(X + (size_t)row * Vv);
  for (int j = tid; j < Vv / 4; j += 256) {
    float4 v = p4[j];
    v.x -= c; v.y -= c; v.z -= c; v.w -= c;
    p4[j] = v;
  }
}

// ---------------- final log-softmax (bf16 logits path): read bf16, write f32 d_out ----------------
__global__ __launch_bounds__(256) void lsm_final2_k(float* __restrict__ X,
                                                    const __hip_bfloat16* __restrict__ L,
                                                    const float2* __restrict__ P) {
  const int row = blockIdx.x;
  const int tid = threadIdx.x;
  float m = -3.4e38f, s = 0.f;
  for (int j = tid; j < 500; j += 256) {
    float2 p = P[(size_t)row * 500 + j];
    if (p.x > m) { s = s * __expf(m - p.x) + p.y; m = p.x; }
    else         { s += p.y * __expf(p.x - m); }
  }
  #pragma unroll
  for (int off2 = 32; off2 > 0; off2 >>= 1) {
    float mo = __shfl_down(m, off2);
    float so = __shfl_down(s, off2);
    float M = fmaxf(m, mo);
    s = s * __expf(m - M) + so * __expf(mo - M);
    m = M;
  }
  __shared__ float sm[4], ss[4];
  if ((tid & 63) == 0) { sm[tid >> 6] = m; ss[tid >> 6] = s; }
  __syncthreads();
  const float M4 = fmaxf(fmaxf(sm[0], sm[1]), fmaxf(sm[2], sm[3]));
  const float S = ss[0] * __expf(sm[0] - M4) + ss[1] * __expf(sm[1] - M4) +
                  ss[2] * __expf(sm[2] - M4) + ss[3] * __expf(sm[3] - M4);
  const float c = M4 + __logf(S);
  const short8* p8 = (const short8*)(L + (size_t)row * Vv);
  float4* o4 = (float4*)(X + (size_t)row * Vv);
  for (int j = tid; j < Vv / 8; j += 256) {
    short8 sv = p8[j];
    float4 a, b;
    a.x = __uint_as_float(((unsigned)(unsigned short)sv[0]) << 16) - c;
    a.y = __uint_as_float(((unsigned)(unsigned short)sv[1]) << 16) - c;
    a.z = __uint_as_float(((unsigned)(unsigned short)sv[2]) << 16) - c;
    a.w = __uint_as_float(((unsigned)(unsigned short)sv[3]) << 16) - c;
    b.x = __uint_as_float(((unsigned)(unsigned short)sv[4]) << 16) - c;
    b.y = __uint_as_float(((unsigned)(unsigned short)sv[5]) << 16) - c;
    b.z = __uint_as_float(((unsigned)(unsigned short)sv[6]) << 16) - c;
    b.w = __uint_as_float(((unsigned)(unsigned short)sv[7]) << 16) - c;
    o4[(j << 1)] = a;
    o4[(j << 1) + 1] = b;
  }
}

}  // namespace

extern "C" void kernel_launch(void* const* d_in, const int* in_sizes, int n_in,
                              void* d_out, int out_size, void* d_ws, size_t ws_size,
                              hipStream_t stream) {
  (void)in_sizes; (void)n_in; (void)out_size;
  const int*   in_seq  = (const int*)d_in[0];
  const int*   tgt_seq = (const int*)d_in[1];
  const float* enc_emb = (const float*)d_in[2];
  const float* enc_Wih = (const float*)d_in[3];
  const float* enc_Whh = (const float*)d_in[4];
  const float* enc_bih = (const float*)d_in[5];
  const float* enc_bhh = (const float*)d_in[6];
  const float* dec_emb = (const float*)d_in[7];
  const float* dec_Wih = (const float*)d_in[8];
  const float* dec_Whh = (const float*)d_in[9];
  const float* dec_bih = (const float*)d_in[10];
  const float* dec_bhh = (const float*)d_in[11];
  const float* out_W   = (const float*)d_in[12];
  const float* out_b   = (const float*)d_in[13];
  float* out = (float*)d_out;

  char* ws = (char*)d_ws;
  size_t off = 0;
  auto alloc = [&](size_t bytes) -> void* {
    void* p = (void*)(ws + off);
    off += (bytes + 255) & ~(size_t)255;
    return p;
  };
  uint2* whhB_e            = (uint2*)alloc((size_t)512 * 512 * 8);   // 2MB packed bf16
  uint2* whhB_d            = (uint2*)alloc((size_t)512 * 512 * 8);
  __hip_bfloat16* encWih_bf = (__hip_bfloat16*)alloc((size_t)1536 * 512 * 2);
  __hip_bfloat16* decWih_bf = (__hip_bfloat16*)alloc((size_t)1536 * 1024 * 2);
  __hip_bfloat16* outW_bf   = (__hip_bfloat16*)alloc((size_t)32000 * 512 * 2);
  __hip_bfloat16* encX_bf   = (__hip_bfloat16*)alloc((size_t)2048 * 512 * 2);
  __hip_bfloat16* decX_bf   = (__hip_bfloat16*)alloc((size_t)2048 * 512 * 2);
  float* enc_xp            = (float*)alloc((size_t)2048 * 1536 * 4);
  float* dec_xp            = (float*)alloc((size_t)2048 * 1536 * 4);
  ull* hTag_e              = (ull*)alloc((size_t)2 * 32 * 512 * 8);  // 256KB tagged h (encoder)
  ull* hTag_d              = (ull*)alloc((size_t)2 * 32 * 512 * 8);  // 256KB tagged h (decoder)
  __hip_bfloat16* decOut_bf = (__hip_bfloat16*)alloc((size_t)2048 * 512 * 2);
  float2* partials         = (float2*)alloc((size_t)2048 * 500 * 8); // 8.2MB softmax stats
  __hip_bfloat16* logitsBf  = (__hip_bfloat16*)alloc((size_t)2048 * Vv * 2);  // 131MB (optional)
  const bool bfLogits = (off <= ws_size);

  // --- weight preprocessing (Wih converts + Whh packs; outW cvt fused in enc_fused) ---
  cvt_bf16_k<<<768, 256, 0, stream>>>(enc_Wih, encWih_bf, 1536 * 512 / 4);
  cvt_bf16_k<<<1536, 256, 0, stream>>>(dec_Wih, decWih_bf, 1536 * 1024 / 4);
  pack_whh_bf_k<<<dim3(8, 16), 256, 0, stream>>>(enc_Whh, whhB_e);
  pack_whh_bf_k<<<dim3(8, 16), 256, 0, stream>>>(dec_Whh, whhB_d);

  // --- embeddings ---
  embed_k<<<2048, 128, 0, stream>>>(in_seq, enc_emb, encX_bf, 0);
  embed_k<<<2048, 128, 0, stream>>>(tgt_seq, dec_emb, decX_bf, 1);

  // --- zero BOTH hTag buffers (contiguous, 131072 u32; full-zero = stale-tag fix) ---
  zero_k<<<512, 256, 0, stream>>>((unsigned*)hTag_e, 2 * 2 * 32 * 512 * 2);

  // --- encoder xp = enc_x @ Wih^T + bih : [2048,1536] ---
  gemm_bf16_k<<<192, 256, 0, stream>>>(encX_bf, encWih_bf, enc_xp, nullptr,
                                       512, 512, G3, 512, enc_bih, nullptr, 16);

  // --- FUSED: encoder GRU || dec_xp partial GEMM (no thought term) || outW bf16 cvt ---
  enc_fused_k<<<240, 512, 0, stream>>>(enc_xp, whhB_e, enc_bhh, hTag_e,
                                       decX_bf, decWih_bf, dec_xp, out_W, outW_bf);
  // thought = h(64) w/ tag 64 lives in hTag_e buffer 0 (even parity)

  // --- decoder GRU: thought projection computed in-prologue from hTag_e ---
  gru_dec_k<<<128, 512, 0, stream>>>(dec_xp, whhB_d, dec_bhh,
                                     hTag_e, dec_Wih, dec_bih, hTag_d, decOut_bf);

  if (bfLogits) {
    gemm_bf16_k<<<4000, 256, 0, stream>>>(decOut_bf, outW_bf, nullptr, logitsBf,
                                          512, 512, Vv, 512, out_b, partials, 16);
    lsm_final2_k<<<2048, 256, 0, stream>>>(out, logitsBf, partials);
  } else {
    gemm_bf16_k<<<4000, 256, 0, stream>>>(decOut_bf, outW_bf, out, nullptr,
                                          512, 512, Vv, 512, out_b, partials, 16);
    lsm_final_k<<<2048, 256, 0, stream>>>(out, partials);
  }
}

// Round 13
// 873.532 us; speedup vs baseline: 1.4815x; 1.0650x over previous
//
#include <hip/hip_runtime.h>
#include <hip/hip_bf16.h>
#include <cstdint>
#include <cstddef>

namespace {

constexpr int Hh = 512;
constexpr int G3 = 1536;   // 3*H
constexpr int Bb = 32;
constexpr int Tt = 64;
constexpr int Vv = 32000;

typedef __attribute__((ext_vector_type(8))) short short8;
typedef __attribute__((ext_vector_type(4))) float f32x4;
typedef unsigned long long ull;

__device__ __forceinline__ unsigned bf16bits(float f) {
  union { __hip_bfloat16 h; unsigned short u; } c;
  c.h = __float2bfloat16(f);
  return (unsigned)c.u;
}

// async global->LDS, 16B per lane; LDS dest = wave-uniform base + lane*16
__device__ __forceinline__ void gl_lds16(const void* g, void* l) {
  __builtin_amdgcn_global_load_lds(
      (const __attribute__((address_space(1))) unsigned int*)g,
      (__attribute__((address_space(3))) unsigned int*)l, 16, 0, 0);
}

// ---------------- merged preprocessing: cvt enc_Wih | cvt dec_Wih | pack Whh x2 | zero hTag ----------------
__device__ __forceinline__ void cvt_range(const float* __restrict__ src,
                                          __hip_bfloat16* __restrict__ dst, int i, int n4) {
  if (i >= n4) return;
  float4 v = ((const float4*)src)[i];
  union { __hip_bfloat16 h[4]; uint2 u; } o;
  o.h[0] = __float2bfloat16(v.x);
  o.h[1] = __float2bfloat16(v.y);
  o.h[2] = __float2bfloat16(v.z);
  o.h[3] = __float2bfloat16(v.w);
  ((uint2*)dst)[i] = o.u;
}

__device__ __forceinline__ void pack_whh_core(const float* __restrict__ Whh,
                                              uint2* __restrict__ P, int k0, int i0) {
  __shared__ float tw[3][32][65];
  const int t = threadIdx.x;               // 256
  const int kk = t & 63, r4 = t >> 6;
  for (int ri = r4; ri < 96; ri += 4) {
    const int g = ri >> 5, ii = ri & 31;
    tw[g][ii][kk] = Whh[(size_t)(g * 512 + i0 + ii) * 512 + k0 + kk];
  }
  __syncthreads();
  const int ii = t & 31, kq = t >> 5;
  for (int k2 = kq; k2 < 64; k2 += 8) {
    unsigned rb = bf16bits(tw[0][ii][k2]);
    unsigned zb = bf16bits(tw[1][ii][k2]);
    unsigned nb = bf16bits(tw[2][ii][k2]);
    P[(size_t)(k0 + k2) * 512 + i0 + ii] = make_uint2((zb << 16) | rb, nb);
  }
}

__global__ __launch_bounds__(256) void prep_k(
    const float* __restrict__ enc_Wih, __hip_bfloat16* __restrict__ encWih_bf,
    const float* __restrict__ dec_Wih, __hip_bfloat16* __restrict__ decWih_bf,
    const float* __restrict__ enc_Whh, uint2* __restrict__ whhB_e,
    const float* __restrict__ dec_Whh, uint2* __restrict__ whhB_d,
    uint4* __restrict__ hTagZero) {
  const int blk = blockIdx.x;
  if (blk < 768) {
    cvt_range(enc_Wih, encWih_bf, blk * 256 + threadIdx.x, 1536 * 512 / 4);
  } else if (blk < 2304) {
    cvt_range(dec_Wih, decWih_bf, (blk - 768) * 256 + threadIdx.x, 1536 * 1024 / 4);
  } else if (blk < 2432) {
    const int b = blk - 2304;
    pack_whh_core(enc_Whh, whhB_e, (b & 7) * 64, (b >> 3) * 32);
  } else if (blk < 2560) {
    const int b = blk - 2432;
    pack_whh_core(dec_Whh, whhB_d, (b & 7) * 64, (b >> 3) * 32);
  } else {
    // zero 2 x hTag (contiguous): 131072 u32 = 32768 uint4; 128 blocks x 256 thr x 1 uint4
    const int i = (blk - 2560) * 256 + threadIdx.x;
    hTagZero[i] = make_uint4(0u, 0u, 0u, 0u);
  }
}

// ---------------- embedding gather (optionally relu) -> bf16 [2048][512] ----------------
__global__ void embed_k(const int* __restrict__ idx, const float* __restrict__ emb,
                        __hip_bfloat16* __restrict__ outp, int do_relu) {
  int row = blockIdx.x;            // 0..2047 (= b*64+t)
  int r = idx[row];
  float4 v = ((const float4*)(emb + (size_t)r * Hh))[threadIdx.x];  // 128 thr * 4
  if (do_relu) {
    v.x = fmaxf(v.x, 0.f); v.y = fmaxf(v.y, 0.f);
    v.z = fmaxf(v.z, 0.f); v.w = fmaxf(v.w, 0.f);
  }
  union { __hip_bfloat16 h[4]; uint2 u; } o;
  o.h[0] = __float2bfloat16(v.x);
  o.h[1] = __float2bfloat16(v.y);
  o.h[2] = __float2bfloat16(v.z);
  o.h[3] = __float2bfloat16(v.w);
  ((uint2*)(outp + (size_t)row * Hh))[threadIdx.x] = o.u;
}

// ---------------- bf16 MFMA GEMM (standalone): C = A*B^T (+bias1) ; partials mode -> bf16 C + stats ----------------
__global__ __launch_bounds__(256) void gemm_bf16_k(
    const __hip_bfloat16* __restrict__ A,
    const __hip_bfloat16* __restrict__ B,
    float* __restrict__ C,
    __hip_bfloat16* __restrict__ Cbf,
    int lda, int ldb, int ldc, int K,
    const float* __restrict__ bias1,
    float2* __restrict__ partials,
    int ntm) {
  __shared__ __align__(16) char smem[32768];
  auto sA = (__hip_bfloat16(*)[64])smem;            // [128][64]
  auto sB = (__hip_bfloat16(*)[64])(smem + 16384);  // [128][64]

  // bijective XCD-chunked swizzle
  const unsigned nwg = gridDim.x, gid = blockIdx.x;
  const unsigned q = nwg >> 3, r8 = nwg & 7, xc = gid & 7, jj = gid >> 3;
  const unsigned wg = (xc < r8 ? xc * (q + 1) : r8 * (q + 1) + (xc - r8) * q) + jj;
  const int m0 = (int)(wg % (unsigned)ntm) << 7;
  const int n0 = (int)(wg / (unsigned)ntm) << 7;

  const int tid = threadIdx.x;
  const int l = tid & 63, w = tid >> 6;
  const int wm = (w & 1) << 6, wn = (w >> 1) << 6;
  const int lr = l & 15;
  const int lk = (l >> 4) << 3;
  const int lrow = (w << 3) + (l >> 3);
  const int lcol = (l & 7) << 3;

  f32x4 acc[4][4];
  #pragma unroll
  for (int i = 0; i < 4; ++i)
    #pragma unroll
    for (int j = 0; j < 4; ++j) acc[i][j] = {0.f, 0.f, 0.f, 0.f};

  for (int k0 = 0; k0 < K; k0 += 64) {
    #pragma unroll
    for (int rr = 0; rr < 4; ++rr) {
      gl_lds16(A + (size_t)(m0 + (rr << 5) + lrow) * lda + k0 + lcol, &sA[(rr << 5) + (w << 3)][0]);
      gl_lds16(B + (size_t)(n0 + (rr << 5) + lrow) * ldb + k0 + lcol, &sB[(rr << 5) + (w << 3)][0]);
    }
    __syncthreads();
    #pragma unroll
    for (int kk = 0; kk < 64; kk += 32) {
      short8 aF[4], bF[4];
      #pragma unroll
      for (int ms = 0; ms < 4; ++ms) aF[ms] = *(const short8*)(&sA[wm + (ms << 4) + lr][kk + lk]);
      #pragma unroll
      for (int ns = 0; ns < 4; ++ns) bF[ns] = *(const short8*)(&sB[wn + (ns << 4) + lr][kk + lk]);
      #pragma unroll
      for (int ms = 0; ms < 4; ++ms)
        #pragma unroll
        for (int ns = 0; ns < 4; ++ns)
          acc[ms][ns] = __builtin_amdgcn_mfma_f32_16x16x32_bf16(aF[ms], bF[ns], acc[ms][ns], 0, 0, 0);
    }
    __syncthreads();
  }

  float* sg = (float*)smem + w * 1088;
  const int r2w = l >> 4;
  const int cw = l & 15;
  const int rbase = r2w << 2;
  #pragma unroll
  for (int ms = 0; ms < 4; ++ms) {
    #pragma unroll
    for (int ns = 0; ns < 4; ++ns)
      #pragma unroll
      for (int r = 0; r < 4; ++r) sg[(rbase + r) * 68 + (ns << 4) + lr] = acc[ms][ns][r];
    #pragma unroll
    for (int qq = 0; qq < 4; ++qq) {
      const int srow2 = (qq << 2) + r2w;
      float4 v = *(const float4*)&sg[srow2 * 68 + (cw << 2)];
      const int row = m0 + wm + (ms << 4) + srow2;
      const int col = n0 + wn + (cw << 2);
      if (bias1) {
        float4 b1 = *(const float4*)&bias1[col];
        v.x += b1.x; v.y += b1.y; v.z += b1.z; v.w += b1.w;
      }
      if (partials) {
        float m4 = fmaxf(fmaxf(v.x, v.y), fmaxf(v.z, v.w));
        #pragma unroll
        for (int hop = 1; hop < 16; hop <<= 1) m4 = fmaxf(m4, __shfl_xor(m4, hop));
        float e = __expf(v.x - m4) + __expf(v.y - m4) + __expf(v.z - m4) + __expf(v.w - m4);
        #pragma unroll
        for (int hop = 1; hop < 16; hop <<= 1) e += __shfl_xor(e, hop);
        if (cw == 0) partials[(size_t)row * 500 + ((n0 >> 6) + (wn >> 6))] = make_float2(m4, e);
        union { __hip_bfloat16 h[4]; uint2 u; } o;
        o.h[0] = __float2bfloat16(v.x);
        o.h[1] = __float2bfloat16(v.y);
        o.h[2] = __float2bfloat16(v.z);
        o.h[3] = __float2bfloat16(v.w);
        *(uint2*)&Cbf[(size_t)row * ldc + col] = o.u;
      } else {
        *(float4*)&C[(size_t)row * ldc + col] = v;
      }
    }
  }
}

// ---------------- GRU core: EXACT v5 step structure (proven 296us) + register-hoisted bhh/tp ----------------
// Round-13 change: xp prefetch REVERTED (round-12 A/B isolated it at ~+40us/launch —
// prefetch loads outstanding across the poll serialize with the spin loop).
// xp is loaded IN-TAIL for the current step, v5-style. tp/bhh stay in registers.
// Cross-block protocol (tagged-value h exchange, relaxed agent atomics) byte-identical to v5.
__device__ __forceinline__ void gru_core(
    const int slice, const int bg,
    const float* __restrict__ xp, const uint2* __restrict__ whhB,
    const float* __restrict__ bhh,
    ull* __restrict__ hTag, __hip_bfloat16* __restrict__ dec_out,
    char* smem,
    const ull* __restrict__ thoughtTag,   // null or encoder hTag buf0 (thought w/ tag 64)
    const float* __restrict__ decWih,     // f32 [1536][1024] (only if thoughtTag)
    const float* __restrict__ dec_bih) {  // f32 [1536]       (only if thoughtTag)
  float* sH = (float*)smem;                 // 2048 f32 (8KB)
  float* sRed = (float*)(smem + 8192);      // 512*13 f32 (26.6KB)
  const int tid = threadIdx.x;
  const int i0 = slice << 5;
  const int il = tid & 31, kc = tid >> 5;   // 32 i x 16 k-chunks(32k each)
  const int kb0 = kc << 5;

  // ---- step-invariant weights -> 96 VGPRs ----
  float wrF[32], wzF[32], wnF[32];
  {
    const uint2* wp = whhB + i0 + il;
    #pragma unroll
    for (int k4 = 0; k4 < 8; ++k4) {
      #pragma unroll
      for (int j = 0; j < 4; ++j) {
        const int idx = (k4 << 2) + j;
        uint2 wv = wp[(size_t)(kb0 + idx) << 9];
        wrF[idx] = __uint_as_float(wv.x << 16);
        wzF[idx] = __uint_as_float(wv.x & 0xffff0000u);
        wnF[idx] = __uint_as_float(wv.y << 16);
      }
    }
  }

  // ---- tail invariants: bhh, tp (thought projection) ----
  float bh_r = 0.f, bh_z = 0.f, bh_n = 0.f;
  float tpr = 0.f, tpz = 0.f, tpn = 0.f;
  int gi = 0, bb = 0;
  if (tid < 128) {
    const int b = tid >> 5, i2 = tid & 31;
    gi = i0 + i2;
    bb = (bg << 2) + b;
    bh_r = bhh[gi]; bh_z = bhh[512 + gi]; bh_n = bhh[1024 + gi];
  }
  if (thoughtTag) {
    // relu(thought) for this bg's 4 batches -> sH (value = low 32 bits of tag word)
    #pragma unroll
    for (int j = 0; j < 4; ++j) {
      ull v = __hip_atomic_load(thoughtTag + ((size_t)bg << 11) + (j << 9) + tid,
                                __ATOMIC_RELAXED, __HIP_MEMORY_SCOPE_AGENT);
      sH[(j << 9) + tid] = fmaxf(__uint_as_float((unsigned)v), 0.f);
    }
    __syncthreads();
    // 384 threads: one (batch b, gate-row) output each; dot over k=512 (f32)
    if (tid < 384) {
      const int b = tid / 96, j = tid % 96;
      const int g = j >> 5, i2 = j & 31;
      const int row = g * 512 + i0 + i2;
      const float4* w4 = (const float4*)(decWih + (size_t)row * 1024 + 512);
      const float* th = &sH[b << 9];
      float s = dec_bih[row];
      #pragma unroll 4
      for (int k = 0; k < 128; ++k) {
        float4 w = w4[k];
        float4 t4 = *(const float4*)&th[k << 2];
        s += w.x * t4.x + w.y * t4.y + w.z * t4.z + w.w * t4.w;
      }
      sRed[tid] = s;
    }
    __syncthreads();
    if (tid < 128) {
      const int b = tid >> 5, i2 = tid & 31;
      tpr = sRed[b * 96 + i2];
      tpz = sRed[b * 96 + 32 + i2];
      tpn = sRed[b * 96 + 64 + i2];
    }
    __syncthreads();
  }

  #pragma unroll 1
  for (int t = 0; t < Tt; ++t) {
    // poll + load h(t) from buffer (t parity); tag word = {step<<32 | f32}
    {
      const ull* hb = hTag + ((size_t)(t & 1) << 14) + ((size_t)bg << 11);
      #pragma unroll
      for (int j = 0; j < 4; ++j) {
        const ull* p = hb + (j << 9) + tid;
        ull v = __hip_atomic_load(p, __ATOMIC_RELAXED, __HIP_MEMORY_SCOPE_AGENT);
        while ((unsigned)(v >> 32) != (unsigned)t) {
          __builtin_amdgcn_s_sleep(1);
          v = __hip_atomic_load(p, __ATOMIC_RELAXED, __HIP_MEMORY_SCOPE_AGENT);
        }
        sH[(j << 9) + tid] = __uint_as_float((unsigned)v);
      }
    }
    __syncthreads();   // B0

    float a[12];
    #pragma unroll
    for (int v = 0; v < 12; ++v) a[v] = 0.f;
    #pragma unroll
    for (int k4 = 0; k4 < 8; ++k4) {
      const int kb = kb0 + (k4 << 2);
      float4 hv0 = *(const float4*)&sH[kb];
      float4 hv1 = *(const float4*)&sH[512 + kb];
      float4 hv2 = *(const float4*)&sH[1024 + kb];
      float4 hv3 = *(const float4*)&sH[1536 + kb];
      const float* h0p = (const float*)&hv0;
      const float* h1p = (const float*)&hv1;
      const float* h2p = (const float*)&hv2;
      const float* h3p = (const float*)&hv3;
      #pragma unroll
      for (int j = 0; j < 4; ++j) {
        const int idx = (k4 << 2) + j;
        const float wr = wrF[idx], wz = wzF[idx], wn = wnF[idx];
        a[0]  = fmaf(wr, h0p[j], a[0]);  a[1]  = fmaf(wz, h0p[j], a[1]);  a[2]  = fmaf(wn, h0p[j], a[2]);
        a[3]  = fmaf(wr, h1p[j], a[3]);  a[4]  = fmaf(wz, h1p[j], a[4]);  a[5]  = fmaf(wn, h1p[j], a[5]);
        a[6]  = fmaf(wr, h2p[j], a[6]);  a[7]  = fmaf(wz, h2p[j], a[7]);  a[8]  = fmaf(wn, h2p[j], a[8]);
        a[9]  = fmaf(wr, h3p[j], a[9]);  a[10] = fmaf(wz, h3p[j], a[10]); a[11] = fmaf(wn, h3p[j], a[11]);
      }
    }
    {
      float* red = &sRed[tid * 13];
      #pragma unroll
      for (int v = 0; v < 12; ++v) red[v] = a[v];
    }
    __syncthreads();   // B1

    if (tid < 128) {
      const int b = tid >> 5, i2 = tid & 31;
      float s0 = 0.f, s1 = 0.f, s2 = 0.f;
      #pragma unroll
      for (int kc2 = 0; kc2 < 16; ++kc2) {
        const float* rp = &sRed[(kc2 * 32 + i2) * 13 + b * 3];
        s0 += rp[0]; s1 += rp[1]; s2 += rp[2];
      }
      const float hr = s0 + bh_r;
      const float hz = s1 + bh_z;
      const float hn = s2 + bh_n;
      // v5-style in-tail xp load (round-13: prefetch reverted)
      const size_t m = (size_t)bb * Tt + t;
      const float xr = xp[m * G3 + gi] + tpr;
      const float xz = xp[m * G3 + 512 + gi] + tpz;
      const float xn = xp[m * G3 + 1024 + gi] + tpn;
      const float rg = 1.f / (1.f + __expf(-(xr + hr)));
      const float zg = 1.f / (1.f + __expf(-(xz + hz)));
      const float ng = tanhf(xn + rg * hn);
      const float hnew = (1.f - zg) * ng + zg * sH[(b << 9) + gi];
      ull* dst = hTag + ((size_t)((t + 1) & 1) << 14) + ((size_t)bb << 9) + gi;
      __hip_atomic_store(dst, ((ull)(unsigned)(t + 1) << 32) | (ull)__float_as_uint(hnew),
                         __ATOMIC_RELAXED, __HIP_MEMORY_SCOPE_AGENT);
      if (dec_out) dec_out[((size_t)m << 9) + gi] = __float2bfloat16(hnew);
    }
    __syncthreads();   // B2: protect sH/sRed
  }
}

// ---------------- 128x128 tile GEMM core for a 256-thread half-block (f32 out, no bias) ----------------
__device__ __forceinline__ void gemm_tile_core(
    const int tid, const int m0, const int n0,
    const __hip_bfloat16* __restrict__ A, const __hip_bfloat16* __restrict__ B,
    float* __restrict__ C, int lda, int ldb, int ldc, int K, char* smem) {
  auto sA = (__hip_bfloat16(*)[64])smem;            // [128][64]
  auto sB = (__hip_bfloat16(*)[64])(smem + 16384);  // [128][64]
  const int l = tid & 63, w = tid >> 6;
  const int wm = (w & 1) << 6, wn = (w >> 1) << 6;
  const int lr = l & 15;
  const int lk = (l >> 4) << 3;
  const int lrow = (w << 3) + (l >> 3);
  const int lcol = (l & 7) << 3;

  f32x4 acc[4][4];
  #pragma unroll
  for (int i = 0; i < 4; ++i)
    #pragma unroll
    for (int j = 0; j < 4; ++j) acc[i][j] = {0.f, 0.f, 0.f, 0.f};

  for (int k0 = 0; k0 < K; k0 += 64) {
    #pragma unroll
    for (int rr = 0; rr < 4; ++rr) {
      gl_lds16(A + (size_t)(m0 + (rr << 5) + lrow) * lda + k0 + lcol, &sA[(rr << 5) + (w << 3)][0]);
      gl_lds16(B + (size_t)(n0 + (rr << 5) + lrow) * ldb + k0 + lcol, &sB[(rr << 5) + (w << 3)][0]);
    }
    __syncthreads();
    #pragma unroll
    for (int kk = 0; kk < 64; kk += 32) {
      short8 aF[4], bF[4];
      #pragma unroll
      for (int ms = 0; ms < 4; ++ms) aF[ms] = *(const short8*)(&sA[wm + (ms << 4) + lr][kk + lk]);
      #pragma unroll
      for (int ns = 0; ns < 4; ++ns) bF[ns] = *(const short8*)(&sB[wn + (ns << 4) + lr][kk + lk]);
      #pragma unroll
      for (int ms = 0; ms < 4; ++ms)
        #pragma unroll
        for (int ns = 0; ns < 4; ++ns)
          acc[ms][ns] = __builtin_amdgcn_mfma_f32_16x16x32_bf16(aF[ms], bF[ns], acc[ms][ns], 0, 0, 0);
    }
    __syncthreads();
  }

  float* sg = (float*)smem + w * 1088;
  const int r2w = l >> 4;
  const int cw = l & 15;
  const int rbase = r2w << 2;
  #pragma unroll
  for (int ms = 0; ms < 4; ++ms) {
    #pragma unroll
    for (int ns = 0; ns < 4; ++ns)
      #pragma unroll
      for (int r = 0; r < 4; ++r) sg[(rbase + r) * 68 + (ns << 4) + lr] = acc[ms][ns][r];
    #pragma unroll
    for (int qq = 0; qq < 4; ++qq) {
      const int srow2 = (qq << 2) + r2w;
      float4 v = *(const float4*)&sg[srow2 * 68 + (cw << 2)];
      *(float4*)&C[(size_t)(m0 + wm + (ms << 4) + srow2) * ldc + n0 + wn + (cw << 2)] = v;
    }
  }
}

// ---------------- FUSED: encoder GRU (blocks 0-127) || dec_xp partial GEMM (128-223) || outW cvt (224-239) ----------------
__global__ __launch_bounds__(512, 1) void enc_fused_k(
    const float* __restrict__ enc_xp, const uint2* __restrict__ whhB_e,
    const float* __restrict__ enc_bhh, ull* __restrict__ hTag_e,
    const __hip_bfloat16* __restrict__ decX_bf, const __hip_bfloat16* __restrict__ decWih_bf,
    float* __restrict__ dec_xp,
    const float* __restrict__ out_W, __hip_bfloat16* __restrict__ outW_bf) {
  __shared__ __align__(16) char smem[65536];
  const int blk = blockIdx.x;
  if (blk < 128) {
    gru_core(blk & 15, blk >> 4, enc_xp, whhB_e, enc_bhh, hTag_e, nullptr, smem,
             nullptr, nullptr, nullptr);
  } else if (blk < 224) {
    const int half = threadIdx.x >> 8;                  // 0/1
    const int tile = ((blk - 128) << 1) + half;         // 0..191
    const int m0 = (tile & 15) << 7;                    // 16 m-tiles
    const int n0 = (tile >> 4) << 7;                    // 12 n-tiles
    gemm_tile_core(threadIdx.x & 255, m0, n0, decX_bf, decWih_bf, dec_xp,
                   512, 1024, G3, 512, smem + (half << 15));
  } else {
    const int n4 = Vv * Hh / 4;                         // 4,096,000
    for (int i = ((blk - 224) << 9) + threadIdx.x; i < n4; i += 16 * 512) {
      float4 v = ((const float4*)out_W)[i];
      union { __hip_bfloat16 h[4]; uint2 u; } o;
      o.h[0] = __float2bfloat16(v.x);
      o.h[1] = __float2bfloat16(v.y);
      o.h[2] = __float2bfloat16(v.z);
      o.h[3] = __float2bfloat16(v.w);
      ((uint2*)outW_bf)[i] = o.u;
    }
  }
}

// ---------------- decoder GRU: v5 core + in-prologue thought projection ----------------
__global__ __launch_bounds__(512, 1) void gru_dec_k(
    const float* __restrict__ xp, const uint2* __restrict__ whhB,
    const float* __restrict__ bhh,
    const ull* __restrict__ thoughtTag,   // encoder hTag buf0 (thought, tag 64)
    const float* __restrict__ decWih, const float* __restrict__ dec_bih,
    ull* __restrict__ hTag, __hip_bfloat16* __restrict__ dec_out) {
  __shared__ __align__(16) char smem[34816];
  gru_core(blockIdx.x & 15, blockIdx.x >> 4, xp, whhB, bhh, hTag, dec_out, smem,
           thoughtTag, decWih, dec_bih);
}

// ---------------- final log-softmax (f32 logits fallback): reduce partials, subtract in place ----------------
__global__ __launch_bounds__(256) void lsm_final_k(float* __restrict__ X,
                                                   const float2* __restrict__ P) {
  const int row = blockIdx.x;
  const int tid = threadIdx.x;
  float m = -3.4e38f, s = 0.f;
  for (int j = tid; j < 500; j += 256) {
    float2 p = P[(size_t)row * 500 + j];
    if (p.x > m) { s = s * __expf(m - p.x) + p.y; m = p.x; }
    else         { s += p.y * __expf(p.x - m); }
  }
  #pragma unroll
  for (int off2 = 32; off2 > 0; off2 >>= 1) {
    float mo = __shfl_down(m, off2);
    float so = __shfl_down(s, off2);
    float M = fmaxf(m, mo);
    s = s * __expf(m - M) + so * __expf(mo - M);
    m = M;
  }
  __shared__ float sm[4], ss[4];
  if ((tid & 63) == 0) { sm[tid >> 6] = m; ss[tid >> 6] = s; }
  __syncthreads();
  const float M4 = fmaxf(fmaxf(sm[0], sm[1]), fmaxf(sm[2], sm[3]));
  const float S = ss[0] * __expf(sm[0] - M4) + ss[1] * __expf(sm[1] - M4) +
                  ss[2] * __expf(sm[2] - M4) + ss[3] * __expf(sm[3] - M4);
  const float c = M4 + __logf(S);
  float4* p4 = (float4*)(X + (size_t)row * Vv);
  for (int j = tid; j < Vv / 4; j += 256) {
    float4 v = p4[j];
    v.x -= c; v.y -= c; v.z -= c; v.w -= c;
    p4[j] = v;
  }
}

// ---------------- final log-softmax (bf16 logits path): read bf16, write f32 d_out ----------------
__global__ __launch_bounds__(256) void lsm_final2_k(float* __restrict__ X,
                                                    const __hip_bfloat16* __restrict__ L,
                                                    const float2* __restrict__ P) {
  const int row = blockIdx.x;
  const int tid = threadIdx.x;
  float m = -3.4e38f, s = 0.f;
  for (int j = tid; j < 500; j += 256) {
    float2 p = P[(size_t)row * 500 + j];
    if (p.x > m) { s = s * __expf(m - p.x) + p.y; m = p.x; }
    else         { s += p.y * __expf(p.x - m); }
  }
  #pragma unroll
  for (int off2 = 32; off2 > 0; off2 >>= 1) {
    float mo = __shfl_down(m, off2);
    float so = __shfl_down(s, off2);
    float M = fmaxf(m, mo);
    s = s * __expf(m - M) + so * __expf(mo - M);
    m = M;
  }
  __shared__ float sm[4], ss[4];
  if ((tid & 63) == 0) { sm[tid >> 6] = m; ss[tid >> 6] = s; }
  __syncthreads();
  const float M4 = fmaxf(fmaxf(sm[0], sm[1]), fmaxf(sm[2], sm[3]));
  const float S = ss[0] * __expf(sm[0] - M4) + ss[1] * __expf(sm[1] - M4) +
                  ss[2] * __expf(sm[2] - M4) + ss[3] * __expf(sm[3] - M4);
  const float c = M4 + __logf(S);
  const short8* p8 = (const short8*)(L + (size_t)row * Vv);
  float4* o4 = (float4*)(X + (size_t)row * Vv);
  for (int j = tid; j < Vv / 8; j += 256) {
    short8 sv = p8[j];
    float4 a, b;
    a.x = __uint_as_float(((unsigned)(unsigned short)sv[0]) << 16) - c;
    a.y = __uint_as_float(((unsigned)(unsigned short)sv[1]) << 16) - c;
    a.z = __uint_as_float(((unsigned)(unsigned short)sv[2]) << 16) - c;
    a.w = __uint_as_float(((unsigned)(unsigned short)sv[3]) << 16) - c;
    b.x = __uint_as_float(((unsigned)(unsigned short)sv[4]) << 16) - c;
    b.y = __uint_as_float(((unsigned)(unsigned short)sv[5]) << 16) - c;
    b.z = __uint_as_float(((unsigned)(unsigned short)sv[6]) << 16) - c;
    b.w = __uint_as_float(((unsigned)(unsigned short)sv[7]) << 16) - c;
    o4[(j << 1)] = a;
    o4[(j << 1) + 1] = b;
  }
}

}  // namespace

extern "C" void kernel_launch(void* const* d_in, const int* in_sizes, int n_in,
                              void* d_out, int out_size, void* d_ws, size_t ws_size,
                              hipStream_t stream) {
  (void)in_sizes; (void)n_in; (void)out_size;
  const int*   in_seq  = (const int*)d_in[0];
  const int*   tgt_seq = (const int*)d_in[1];
  const float* enc_emb = (const float*)d_in[2];
  const float* enc_Wih = (const float*)d_in[3];
  const float* enc_Whh = (const float*)d_in[4];
  const float* enc_bih = (const float*)d_in[5];
  const float* enc_bhh = (const float*)d_in[6];
  const float* dec_emb = (const float*)d_in[7];
  const float* dec_Wih = (const float*)d_in[8];
  const float* dec_Whh = (const float*)d_in[9];
  const float* dec_bih = (const float*)d_in[10];
  const float* dec_bhh = (const float*)d_in[11];
  const float* out_W   = (const float*)d_in[12];
  const float* out_b   = (const float*)d_in[13];
  float* out = (float*)d_out;

  char* ws = (char*)d_ws;
  size_t off = 0;
  auto alloc = [&](size_t bytes) -> void* {
    void* p = (void*)(ws + off);
    off += (bytes + 255) & ~(size_t)255;
    return p;
  };
  uint2* whhB_e            = (uint2*)alloc((size_t)512 * 512 * 8);   // 2MB packed bf16
  uint2* whhB_d            = (uint2*)alloc((size_t)512 * 512 * 8);
  __hip_bfloat16* encWih_bf = (__hip_bfloat16*)alloc((size_t)1536 * 512 * 2);
  __hip_bfloat16* decWih_bf = (__hip_bfloat16*)alloc((size_t)1536 * 1024 * 2);
  __hip_bfloat16* outW_bf   = (__hip_bfloat16*)alloc((size_t)32000 * 512 * 2);
  __hip_bfloat16* encX_bf   = (__hip_bfloat16*)alloc((size_t)2048 * 512 * 2);
  __hip_bfloat16* decX_bf   = (__hip_bfloat16*)alloc((size_t)2048 * 512 * 2);
  float* enc_xp            = (float*)alloc((size_t)2048 * 1536 * 4);
  float* dec_xp            = (float*)alloc((size_t)2048 * 1536 * 4);
  ull* hTag_e              = (ull*)alloc((size_t)2 * 32 * 512 * 8);  // 256KB tagged h (encoder)
  ull* hTag_d              = (ull*)alloc((size_t)2 * 32 * 512 * 8);  // 256KB tagged h (decoder)
  __hip_bfloat16* decOut_bf = (__hip_bfloat16*)alloc((size_t)2048 * 512 * 2);
  float2* partials         = (float2*)alloc((size_t)2048 * 500 * 8); // 8.2MB softmax stats
  __hip_bfloat16* logitsBf  = (__hip_bfloat16*)alloc((size_t)2048 * Vv * 2);  // 131MB (optional)
  const bool bfLogits = (off <= ws_size);

  // --- merged preprocessing: cvt x2 | pack x2 | zero both hTag buffers (contiguous) ---
  prep_k<<<2688, 256, 0, stream>>>(enc_Wih, encWih_bf, dec_Wih, decWih_bf,
                                   enc_Whh, whhB_e, dec_Whh, whhB_d, (uint4*)hTag_e);

  // --- embeddings ---
  embed_k<<<2048, 128, 0, stream>>>(in_seq, enc_emb, encX_bf, 0);
  embed_k<<<2048, 128, 0, stream>>>(tgt_seq, dec_emb, decX_bf, 1);

  // --- encoder xp = enc_x @ Wih^T + bih : [2048,1536] ---
  gemm_bf16_k<<<192, 256, 0, stream>>>(encX_bf, encWih_bf, enc_xp, nullptr,
                                       512, 512, G3, 512, enc_bih, nullptr, 16);

  // --- FUSED: encoder GRU || dec_xp partial GEMM (no thought term) || outW bf16 cvt ---
  enc_fused_k<<<240, 512, 0, stream>>>(enc_xp, whhB_e, enc_bhh, hTag_e,
                                       decX_bf, decWih_bf, dec_xp, out_W, outW_bf);
  // thought = h(64) w/ tag 64 lives in hTag_e buffer 0 (even parity)

  // --- decoder GRU: thought projection computed in-prologue from hTag_e ---
  gru_dec_k<<<128, 512, 0, stream>>>(dec_xp, whhB_d, dec_bhh,
                                     hTag_e, dec_Wih, dec_bih, hTag_d, decOut_bf);

  if (bfLogits) {
    gemm_bf16_k<<<4000, 256, 0, stream>>>(decOut_bf, outW_bf, nullptr, logitsBf,
                                          512, 512, Vv, 512, out_b, partials, 16);
    lsm_final2_k<<<2048, 256, 0, stream>>>(out, logitsBf, partials);
  } else {
    gemm_bf16_k<<<4000, 256, 0, stream>>>(decOut_bf, outW_bf, out, nullptr,
                                          512, 512, Vv, 512, out_b, partials, 16);
    lsm_final_k<<<2048, 256, 0, stream>>>(out, partials);
  }
}